// Round 1
// baseline (811.627 us; speedup 1.0000x reference)
//
#include <hip/hip_runtime.h>
#include <math.h>

// Problem constants (from reference)
constexpr int Nn  = 50000;   // nodes
constexpr int FIN = 128;     // input features
constexpr int NH  = 8;       // heads
constexpr int FO  = 16;      // features per head
constexpr int HF  = 128;     // NH*FO

// ---------------------------------------------------------------------------
// Kernel: ctp[h] = sum_f Wt[h*FO+f] * a_tp[h*FO+f]
// (s_tp[e,h] = edge_prob[e] * ctp[h])
// ---------------------------------------------------------------------------
__global__ void k_ctp(const float* __restrict__ Wt,
                      const float* __restrict__ a_tp,
                      float* __restrict__ ctp) {
    int h = threadIdx.x;
    if (h < NH) {
        float s = 0.f;
        #pragma unroll
        for (int f = 0; f < FO; ++f) s += Wt[h * FO + f] * a_tp[h * FO + f];
        ctp[h] = s;
    }
}

// ---------------------------------------------------------------------------
// Kernel: per-node projections.
//   proj[n,:] = x[n,:] @ Wp^T          (stored to ws)
//   acc[n,:]  = x[n,:] @ Wskip^T       (skip connection, seeds the output acc)
//   s_src[n,h] = sum_f proj[n,h,f]*a_src[h,f]
//   s_trg[n,h] = sum_f proj[n,h,f]*a_trg[h,f]
// Block: 128 threads (one per output dim o), NB=8 nodes per block.
// ---------------------------------------------------------------------------
__global__ __launch_bounds__(128) void k_node(
    const float* __restrict__ x,
    const float* __restrict__ Wp, const float* __restrict__ Wskip,
    const float* __restrict__ a_src, const float* __restrict__ a_trg,
    float* __restrict__ proj, float* __restrict__ acc,
    float* __restrict__ s_src, float* __restrict__ s_trg)
{
    constexpr int NB = 8;
    __shared__ float xs[NB][FIN];
    const int o  = threadIdx.x;        // 0..127
    const int n0 = blockIdx.x * NB;

    #pragma unroll
    for (int i = 0; i < NB; ++i) xs[i][o] = x[(n0 + i) * FIN + o];
    __syncthreads();

    float accP[NB], accS[NB];
    #pragma unroll
    for (int i = 0; i < NB; ++i) { accP[i] = 0.f; accS[i] = 0.f; }

    const float4* Wp4 = reinterpret_cast<const float4*>(Wp)    + o * (FIN / 4);
    const float4* Ws4 = reinterpret_cast<const float4*>(Wskip) + o * (FIN / 4);

    for (int k4 = 0; k4 < FIN / 4; ++k4) {
        float4 wp = Wp4[k4];
        float4 wsv = Ws4[k4];
        int k = k4 * 4;
        #pragma unroll
        for (int i = 0; i < NB; ++i) {
            float x0 = xs[i][k], x1 = xs[i][k + 1], x2 = xs[i][k + 2], x3 = xs[i][k + 3];
            accP[i] += x0 * wp.x + x1 * wp.y + x2 * wp.z + x3 * wp.w;
            accS[i] += x0 * wsv.x + x1 * wsv.y + x2 * wsv.z + x3 * wsv.w;
        }
    }

    const float asrc = a_src[o];   // a_src flat [H][FO], index h*16+f == o
    const float atrg = a_trg[o];
    const int h = o >> 4;

    #pragma unroll
    for (int i = 0; i < NB; ++i) {
        const int n = n0 + i;
        proj[n * HF + o] = accP[i];
        acc[n * HF + o]  = accS[i];
        float vs = accP[i] * asrc;
        float vt = accP[i] * atrg;
        // reduce over the 16 lanes of this head (lanes h*16..h*16+15 contiguous)
        #pragma unroll
        for (int m = 8; m >= 1; m >>= 1) {
            vs += __shfl_xor(vs, m, 16);
            vt += __shfl_xor(vt, m, 16);
        }
        if ((o & 15) == 0) {
            s_src[n * NH + h] = vs;
            s_trg[n * NH + h] = vt;
        }
    }
}

// ---------------------------------------------------------------------------
// Kernel: edge pass 1 — accumulate softmax denominators per (trg, head).
// One thread per edge; 8 atomics/edge.
// Note: no max-shift needed — scores are O(5) for this data distribution and
// the global max-shift cancels in attn = e/denom (1e-16 term negligible).
// ---------------------------------------------------------------------------
__global__ __launch_bounds__(256) void k_edge_denom(
    const int* __restrict__ src, const int* __restrict__ trg,
    const float* __restrict__ prob,
    const float* __restrict__ s_src, const float* __restrict__ s_trg,
    const float* __restrict__ ctp, float* __restrict__ denom, int E)
{
    int e = blockIdx.x * blockDim.x + threadIdx.x;
    if (e >= E) return;
    int s = src[e], t = trg[e];
    float p = prob[e];
    float4 ss0 = *reinterpret_cast<const float4*>(s_src + s * NH);
    float4 ss1 = *reinterpret_cast<const float4*>(s_src + s * NH + 4);
    float4 st0 = *reinterpret_cast<const float4*>(s_trg + t * NH);
    float4 st1 = *reinterpret_cast<const float4*>(s_trg + t * NH + 4);
    float ssv[8] = {ss0.x, ss0.y, ss0.z, ss0.w, ss1.x, ss1.y, ss1.z, ss1.w};
    float stv[8] = {st0.x, st0.y, st0.z, st0.w, st1.x, st1.y, st1.z, st1.w};
    #pragma unroll
    for (int h = 0; h < NH; ++h) {
        float sc = ssv[h] + stv[h] + ctp[h] * p;
        sc = sc >= 0.f ? sc : 0.2f * sc;
        atomicAdd(&denom[t * NH + h], __expf(sc));
    }
}

// ---------------------------------------------------------------------------
// Kernel: edge pass 2 — scatter weighted source projections.
// 128 threads per edge (one per output dim), 2 edges per 256-thread block.
// Recomputes the score (cheaper than storing E*H exp values in ws).
// ---------------------------------------------------------------------------
__global__ __launch_bounds__(256) void k_edge_scatter(
    const int* __restrict__ src, const int* __restrict__ trg,
    const float* __restrict__ prob,
    const float* __restrict__ s_src, const float* __restrict__ s_trg,
    const float* __restrict__ ctp, const float* __restrict__ denom,
    const float* __restrict__ proj, float* __restrict__ acc, int E)
{
    int tid = threadIdx.x;
    int e = blockIdx.x * 2 + (tid >> 7);
    if (e >= E) return;
    int o = tid & 127;
    int h = o >> 4;
    int s = src[e], t = trg[e];
    float p = prob[e];
    float sc = s_src[s * NH + h] + s_trg[t * NH + h] + ctp[h] * p;
    sc = sc >= 0.f ? sc : 0.2f * sc;
    float attn = __expf(sc) / (denom[t * NH + h] + 1e-16f);
    atomicAdd(&acc[t * HF + o], proj[s * HF + o] * attn);
}

// ---------------------------------------------------------------------------
// Kernel: epilogue — out = elu(acc + bias)
// ---------------------------------------------------------------------------
__global__ __launch_bounds__(256) void k_final(
    const float* __restrict__ acc, const float* __restrict__ bias,
    float* __restrict__ out, int total)
{
    int i = blockIdx.x * blockDim.x + threadIdx.x;
    if (i >= total) return;
    float v = acc[i] + bias[i & (HF - 1)];
    out[i] = v > 0.f ? v : expm1f(v);
}

// ---------------------------------------------------------------------------
extern "C" void kernel_launch(void* const* d_in, const int* in_sizes, int n_in,
                              void* d_out, int out_size, void* d_ws, size_t ws_size,
                              hipStream_t stream)
{
    const float* x     = (const float*)d_in[0];
    const int*   ei    = (const int*)d_in[1];
    const float* prob  = (const float*)d_in[2];
    const float* Wp    = (const float*)d_in[3];
    const float* Wt    = (const float*)d_in[4];
    const float* a_src = (const float*)d_in[5];
    const float* a_trg = (const float*)d_in[6];
    const float* a_tp  = (const float*)d_in[7];
    const float* Wskip = (const float*)d_in[8];
    const float* bias  = (const float*)d_in[9];
    float* out = (float*)d_out;

    const int E = in_sizes[2];        // edge_prob element count = E
    const int* src = ei;              // edge_index row 0
    const int* trg = ei + E;          // edge_index row 1

    // Workspace layout (floats): proj | acc | s_src | s_trg | denom | ctp
    float* ws    = (float*)d_ws;
    float* proj  = ws;                       // Nn*HF
    float* acc   = proj  + (size_t)Nn * HF;  // Nn*HF
    float* s_src = acc   + (size_t)Nn * HF;  // Nn*NH
    float* s_trg = s_src + (size_t)Nn * NH;  // Nn*NH
    float* denom = s_trg + (size_t)Nn * NH;  // Nn*NH
    float* ctp   = denom + (size_t)Nn * NH;  // NH
    // total ~56 MB

    hipMemsetAsync(denom, 0, (size_t)Nn * NH * sizeof(float), stream);
    k_ctp<<<1, 64, 0, stream>>>(Wt, a_tp, ctp);
    k_node<<<Nn / 8, 128, 0, stream>>>(x, Wp, Wskip, a_src, a_trg,
                                       proj, acc, s_src, s_trg);
    k_edge_denom<<<(E + 255) / 256, 256, 0, stream>>>(src, trg, prob,
                                                      s_src, s_trg, ctp, denom, E);
    k_edge_scatter<<<(E + 1) / 2, 256, 0, stream>>>(src, trg, prob, s_src, s_trg,
                                                    ctp, denom, proj, acc, E);
    k_final<<<(Nn * HF + 255) / 256, 256, 0, stream>>>(acc, bias, out, Nn * HF);
}

// Round 2
// 553.279 us; speedup vs baseline: 1.4669x; 1.4669x over previous
//
#include <hip/hip_runtime.h>
#include <math.h>

// Problem constants (from reference)
constexpr int Nn  = 50000;   // nodes
constexpr int FIN = 128;     // input features
constexpr int NH  = 8;       // heads
constexpr int FO  = 16;      // features per head
constexpr int HF  = 128;     // NH*FO

// ---------------------------------------------------------------------------
// ctp[h] = sum_f Wt[h*FO+f] * a_tp[h*FO+f]   (s_tp[e,h] = edge_prob[e]*ctp[h])
// ---------------------------------------------------------------------------
__global__ void k_ctp(const float* __restrict__ Wt,
                      const float* __restrict__ a_tp,
                      float* __restrict__ ctp) {
    int h = threadIdx.x;
    if (h < NH) {
        float s = 0.f;
        #pragma unroll
        for (int f = 0; f < FO; ++f) s += Wt[h * FO + f] * a_tp[h * FO + f];
        ctp[h] = s;
    }
}

// ---------------------------------------------------------------------------
// Per-node projections: proj = x@Wp^T, skip = x@Wskip^T, s_src/s_trg scores.
// ---------------------------------------------------------------------------
__global__ __launch_bounds__(128) void k_node(
    const float* __restrict__ x,
    const float* __restrict__ Wp, const float* __restrict__ Wskip,
    const float* __restrict__ a_src, const float* __restrict__ a_trg,
    float* __restrict__ proj, float* __restrict__ skip,
    float* __restrict__ s_src, float* __restrict__ s_trg)
{
    constexpr int NB = 8;
    __shared__ float xs[NB][FIN];
    const int o  = threadIdx.x;        // 0..127
    const int n0 = blockIdx.x * NB;

    #pragma unroll
    for (int i = 0; i < NB; ++i) xs[i][o] = x[(n0 + i) * FIN + o];
    __syncthreads();

    float accP[NB], accS[NB];
    #pragma unroll
    for (int i = 0; i < NB; ++i) { accP[i] = 0.f; accS[i] = 0.f; }

    const float4* Wp4 = reinterpret_cast<const float4*>(Wp)    + o * (FIN / 4);
    const float4* Ws4 = reinterpret_cast<const float4*>(Wskip) + o * (FIN / 4);

    for (int k4 = 0; k4 < FIN / 4; ++k4) {
        float4 wp = Wp4[k4];
        float4 wsv = Ws4[k4];
        int k = k4 * 4;
        #pragma unroll
        for (int i = 0; i < NB; ++i) {
            float x0 = xs[i][k], x1 = xs[i][k + 1], x2 = xs[i][k + 2], x3 = xs[i][k + 3];
            accP[i] += x0 * wp.x + x1 * wp.y + x2 * wp.z + x3 * wp.w;
            accS[i] += x0 * wsv.x + x1 * wsv.y + x2 * wsv.z + x3 * wsv.w;
        }
    }

    const float asrc = a_src[o];   // flat [H][FO]: index h*16+f == o
    const float atrg = a_trg[o];
    const int h = o >> 4;

    #pragma unroll
    for (int i = 0; i < NB; ++i) {
        const int n = n0 + i;
        proj[n * HF + o] = accP[i];
        skip[n * HF + o] = accS[i];
        float vs = accP[i] * asrc;
        float vt = accP[i] * atrg;
        #pragma unroll
        for (int m = 8; m >= 1; m >>= 1) {
            vs += __shfl_xor(vs, m, 16);
            vt += __shfl_xor(vt, m, 16);
        }
        if ((o & 15) == 0) {
            s_src[n * NH + h] = vs;
            s_trg[n * NH + h] = vt;
        }
    }
}

// ---------------------------------------------------------------------------
// CSR build (by target): count -> scan -> fill
// ---------------------------------------------------------------------------
__global__ __launch_bounds__(256) void k_count(const int* __restrict__ trg,
                                               int* __restrict__ deg, int E)
{
    int e = blockIdx.x * blockDim.x + threadIdx.x;
    if (e < E) atomicAdd(&deg[trg[e]], 1);
}

// Single-block hierarchical exclusive scan of deg[Nn] -> rowptr[Nn+1], pos[Nn]
__global__ __launch_bounds__(1024) void k_scan(const int* __restrict__ deg,
                                               int* __restrict__ rowptr,
                                               int* __restrict__ pos)
{
    __shared__ int lds[1024];
    const int t  = threadIdx.x;
    const int CH = (Nn + 1023) / 1024;           // 49
    const int lo = t * CH;
    const int hi = min(lo + CH, Nn);

    int s = 0;
    for (int i = lo; i < hi; ++i) s += deg[i];
    lds[t] = s;
    __syncthreads();
    for (int off = 1; off < 1024; off <<= 1) {
        int v = (t >= off) ? lds[t - off] : 0;
        __syncthreads();
        lds[t] += v;
        __syncthreads();
    }
    int base = lds[t] - s;                        // exclusive prefix
    for (int i = lo; i < hi; ++i) {
        rowptr[i] = base;
        pos[i]    = base;
        base += deg[i];
    }
    if (t == 1023) rowptr[Nn] = base;             // == E
}

__global__ __launch_bounds__(256) void k_fill(const int* __restrict__ trg,
                                              int* __restrict__ pos,
                                              int* __restrict__ eid, int E)
{
    int e = blockIdx.x * blockDim.x + threadIdx.x;
    if (e < E) {
        int slot = atomicAdd(&pos[trg[e]], 1);
        eid[slot] = e;
    }
}

// ---------------------------------------------------------------------------
// Gather: per target node, accumulate softmax numerator+denominator in
// registers over its in-edges, then write final ELU output. No atomics.
// 128 threads per node (one per output dim), 2 nodes per 256-thread block.
// ---------------------------------------------------------------------------
__global__ __launch_bounds__(256) void k_gather(
    const int* __restrict__ src, const float* __restrict__ prob,
    const int* __restrict__ eid, const int* __restrict__ rowptr,
    const float* __restrict__ s_src, const float* __restrict__ s_trg,
    const float* __restrict__ ctp,
    const float* __restrict__ proj, const float* __restrict__ skip,
    const float* __restrict__ bias, float* __restrict__ out)
{
    const int tid = threadIdx.x;
    const int n = blockIdx.x * 2 + (tid >> 7);
    if (n >= Nn) return;
    const int o = tid & 127;
    const int h = o >> 4;

    const int jb = rowptr[n], je = rowptr[n + 1];
    const float st  = s_trg[n * NH + h];
    const float cth = ctp[h];
    float num = 0.f, den = 0.f;

    for (int j = jb; j < je; ++j) {
        const int   e = eid[j];
        const int   s = src[e];
        const float p = prob[e];
        float sc = s_src[s * NH + h] + st + cth * p;
        sc = sc >= 0.f ? sc : 0.2f * sc;
        const float ev = __expf(sc);
        num += ev * proj[s * HF + o];
        den += ev;
    }
    float v = skip[n * HF + o] + num / (den + 1e-16f) + bias[o];
    out[n * HF + o] = v > 0.f ? v : expm1f(v);
}

// ---------------------------------------------------------------------------
extern "C" void kernel_launch(void* const* d_in, const int* in_sizes, int n_in,
                              void* d_out, int out_size, void* d_ws, size_t ws_size,
                              hipStream_t stream)
{
    const float* x     = (const float*)d_in[0];
    const int*   ei    = (const int*)d_in[1];
    const float* prob  = (const float*)d_in[2];
    const float* Wp    = (const float*)d_in[3];
    const float* Wt    = (const float*)d_in[4];
    const float* a_src = (const float*)d_in[5];
    const float* a_trg = (const float*)d_in[6];
    const float* a_tp  = (const float*)d_in[7];
    const float* Wskip = (const float*)d_in[8];
    const float* bias  = (const float*)d_in[9];
    float* out = (float*)d_out;

    const int E = in_sizes[2];        // edge_prob element count = E
    const int* src = ei;              // edge_index row 0
    const int* trg = ei + E;          // edge_index row 1

    // Workspace layout
    float* ws     = (float*)d_ws;
    float* proj   = ws;                        // Nn*HF
    float* skip   = proj  + (size_t)Nn * HF;   // Nn*HF
    float* s_src  = skip  + (size_t)Nn * HF;   // Nn*NH
    float* s_trg  = s_src + (size_t)Nn * NH;   // Nn*NH
    float* ctp    = s_trg + (size_t)Nn * NH;   // 16 (8 used, padded)
    int*   deg    = (int*)(ctp + 16);          // Nn
    int*   rowptr = deg + Nn;                  // Nn+1
    int*   pos    = rowptr + Nn + 1;           // Nn
    int*   eid    = pos + Nn;                  // E
    // total ~58.3 MB

    hipMemsetAsync(deg, 0, (size_t)Nn * sizeof(int), stream);
    k_ctp<<<1, 64, 0, stream>>>(Wt, a_tp, ctp);
    k_node<<<Nn / 8, 128, 0, stream>>>(x, Wp, Wskip, a_src, a_trg,
                                       proj, skip, s_src, s_trg);
    k_count<<<(E + 255) / 256, 256, 0, stream>>>(trg, deg, E);
    k_scan<<<1, 1024, 0, stream>>>(deg, rowptr, pos);
    k_fill<<<(E + 255) / 256, 256, 0, stream>>>(trg, pos, eid, E);
    k_gather<<<(Nn + 1) / 2, 256, 0, stream>>>(src, prob, eid, rowptr,
                                               s_src, s_trg, ctp, proj, skip,
                                               bias, out);
}

// Round 3
// 426.659 us; speedup vs baseline: 1.9023x; 1.2968x over previous
//
#include <hip/hip_runtime.h>
#include <math.h>

// Problem constants (from reference)
constexpr int Nn  = 50000;   // nodes
constexpr int FIN = 128;     // input features
constexpr int NH  = 8;       // heads
constexpr int FO  = 16;      // features per head
constexpr int HF  = 128;     // NH*FO
constexpr int NBLK_PER_HEAD = (Nn + 3) / 4;     // 12500 (4 nodes per 256-thr block)
constexpr int NSCAN = (Nn + 255) / 256;         // 196 scan blocks

// ---------------------------------------------------------------------------
// ctp[h] = sum_f Wt[h*FO+f] * a_tp[h*FO+f]   (s_tp[e,h] = edge_prob[e]*ctp[h])
// ---------------------------------------------------------------------------
__global__ void k_ctp(const float* __restrict__ Wt,
                      const float* __restrict__ a_tp,
                      float* __restrict__ ctp) {
    int h = threadIdx.x;
    if (h < NH) {
        float s = 0.f;
        #pragma unroll
        for (int f = 0; f < FO; ++f) s += Wt[h * FO + f] * a_tp[h * FO + f];
        ctp[h] = s;
    }
}

// ---------------------------------------------------------------------------
// Per-node projections.
//   projH[h][n][f] = (x @ Wp^T) head-major     (3.2 MB per head slice)
//   out[n][o]      = (x @ Wskip^T) + bias      (pre-activation accumulator)
//   s_srcT[h][n], s_trgT[h][n]                 (head-major score vectors)
// ---------------------------------------------------------------------------
__global__ __launch_bounds__(128) void k_node(
    const float* __restrict__ x,
    const float* __restrict__ Wp, const float* __restrict__ Wskip,
    const float* __restrict__ a_src, const float* __restrict__ a_trg,
    const float* __restrict__ bias,
    float* __restrict__ projH, float* __restrict__ out,
    float* __restrict__ s_srcT, float* __restrict__ s_trgT)
{
    constexpr int NB = 8;
    __shared__ float xs[NB][FIN];
    const int o  = threadIdx.x;        // 0..127
    const int n0 = blockIdx.x * NB;

    #pragma unroll
    for (int i = 0; i < NB; ++i) xs[i][o] = x[(n0 + i) * FIN + o];
    __syncthreads();

    float accP[NB], accS[NB];
    #pragma unroll
    for (int i = 0; i < NB; ++i) { accP[i] = 0.f; accS[i] = 0.f; }

    const float4* Wp4 = reinterpret_cast<const float4*>(Wp)    + o * (FIN / 4);
    const float4* Ws4 = reinterpret_cast<const float4*>(Wskip) + o * (FIN / 4);

    for (int k4 = 0; k4 < FIN / 4; ++k4) {
        float4 wp = Wp4[k4];
        float4 wsv = Ws4[k4];
        int k = k4 * 4;
        #pragma unroll
        for (int i = 0; i < NB; ++i) {
            float x0 = xs[i][k], x1 = xs[i][k + 1], x2 = xs[i][k + 2], x3 = xs[i][k + 3];
            accP[i] += x0 * wp.x + x1 * wp.y + x2 * wp.z + x3 * wp.w;
            accS[i] += x0 * wsv.x + x1 * wsv.y + x2 * wsv.z + x3 * wsv.w;
        }
    }

    const float asrc = a_src[o];   // flat [H][FO]: index h*16+f == o
    const float atrg = a_trg[o];
    const float bo   = bias[o];
    const int h = o >> 4;
    const int f = o & 15;

    #pragma unroll
    for (int i = 0; i < NB; ++i) {
        const int n = n0 + i;
        projH[((size_t)h * Nn + n) * FO + f] = accP[i];
        out[n * HF + o] = accS[i] + bo;
        float vs = accP[i] * asrc;
        float vt = accP[i] * atrg;
        #pragma unroll
        for (int m = 8; m >= 1; m >>= 1) {
            vs += __shfl_xor(vs, m, 16);
            vt += __shfl_xor(vt, m, 16);
        }
        if (f == 0) {
            s_srcT[h * Nn + n] = vs;
            s_trgT[h * Nn + n] = vt;
        }
    }
}

// ---------------------------------------------------------------------------
// CSR build (by target): count -> 3-phase scan -> fill (writes sorted arrays)
// ---------------------------------------------------------------------------
__global__ __launch_bounds__(256) void k_count(const int* __restrict__ trg,
                                               int* __restrict__ deg, int E)
{
    int e = blockIdx.x * blockDim.x + threadIdx.x;
    if (e < E) atomicAdd(&deg[trg[e]], 1);
}

__global__ __launch_bounds__(256) void k_scan1(const int* __restrict__ deg,
                                               int* __restrict__ partial)
{
    __shared__ int lds[256];
    int t = threadIdx.x, i = blockIdx.x * 256 + t;
    lds[t] = (i < Nn) ? deg[i] : 0;
    __syncthreads();
    for (int off = 128; off > 0; off >>= 1) {
        if (t < off) lds[t] += lds[t + off];
        __syncthreads();
    }
    if (t == 0) partial[blockIdx.x] = lds[0];
}

__global__ __launch_bounds__(256) void k_scan2(const int* __restrict__ partial,
                                               int* __restrict__ base)
{
    __shared__ int lds[256];
    int t = threadIdx.x;
    int v = (t < NSCAN) ? partial[t] : 0;
    lds[t] = v;
    __syncthreads();
    for (int off = 1; off < 256; off <<= 1) {
        int u = (t >= off) ? lds[t - off] : 0;
        __syncthreads();
        lds[t] += u;
        __syncthreads();
    }
    if (t < NSCAN) base[t] = lds[t] - v;   // exclusive prefix of partials
}

__global__ __launch_bounds__(256) void k_scan3(const int* __restrict__ deg,
                                               const int* __restrict__ base,
                                               int* __restrict__ pos)
{
    __shared__ int lds[256];
    int t = threadIdx.x, i = blockIdx.x * 256 + t;
    int v = (i < Nn) ? deg[i] : 0;
    lds[t] = v;
    __syncthreads();
    for (int off = 1; off < 256; off <<= 1) {
        int u = (t >= off) ? lds[t - off] : 0;
        __syncthreads();
        lds[t] += u;
        __syncthreads();
    }
    if (i < Nn) pos[i] = base[blockIdx.x] + lds[t] - v;   // exclusive prefix
}

// fill: pos[n] bumps from exclusive to inclusive prefix; afterwards
// row n spans [ (n?pos[n-1]:0), pos[n] ) in the sorted arrays.
__global__ __launch_bounds__(256) void k_fill(
    const int* __restrict__ src, const int* __restrict__ trg,
    const float* __restrict__ prob, int* __restrict__ pos,
    int* __restrict__ srcS, float* __restrict__ probS, int E)
{
    int e = blockIdx.x * blockDim.x + threadIdx.x;
    if (e < E) {
        int slot = atomicAdd(&pos[trg[e]], 1);
        srcS[slot] = src[e];
        probS[slot] = prob[e];
    }
}

// ---------------------------------------------------------------------------
// Gather, head-partitioned. One wave per (node, head); lanes = 4 edge-slots
// x 16 features. Heads processed phase-sequentially (h = bid / NBLK_PER_HEAD)
// so each XCD L2 holds one 3.2 MB projH slice at a time. No atomics.
// ---------------------------------------------------------------------------
__global__ __launch_bounds__(256) void k_gather(
    const int* __restrict__ srcS, const float* __restrict__ probS,
    const int* __restrict__ pos,
    const float* __restrict__ s_srcT, const float* __restrict__ s_trgT,
    const float* __restrict__ ctp, const float* __restrict__ projH,
    float* __restrict__ out)
{
    const int bid = blockIdx.x;
    const int h   = bid / NBLK_PER_HEAD;
    const int nb  = bid - h * NBLK_PER_HEAD;
    const int wv  = threadIdx.x >> 6;
    const int lane = threadIdx.x & 63;
    const int n = nb * 4 + wv;                 // 50000 = 12500*4, always valid
    const int es = lane >> 4;                  // edge slot 0..3
    const int f  = lane & 15;                  // feature 0..15

    const int jb = (n == 0) ? 0 : pos[n - 1];
    const int je = pos[n];
    const float st  = s_trgT[h * Nn + n];
    const float cth = ctp[h];
    const float* __restrict__ psl = projH + (size_t)h * Nn * FO;
    const float* __restrict__ ssl = s_srcT + h * Nn;

    float num = 0.f, den = 0.f;
    for (int j = jb + es; j < je; j += 4) {
        const int   s = srcS[j];
        const float p = probS[j];
        float sc = ssl[s] + st + cth * p;
        sc = sc >= 0.f ? sc : 0.2f * sc;
        const float ev = __expf(sc);
        den += ev;
        num += ev * psl[s * FO + f];
    }
    num += __shfl_xor(num, 16, 64);
    den += __shfl_xor(den, 16, 64);
    num += __shfl_xor(num, 32, 64);
    den += __shfl_xor(den, 32, 64);

    if (es == 0) {
        const int idx = n * HF + h * FO + f;
        float v = out[idx] + num / (den + 1e-16f);   // out holds skip+bias
        out[idx] = v > 0.f ? v : expm1f(v);
    }
}

// ---------------------------------------------------------------------------
extern "C" void kernel_launch(void* const* d_in, const int* in_sizes, int n_in,
                              void* d_out, int out_size, void* d_ws, size_t ws_size,
                              hipStream_t stream)
{
    const float* x     = (const float*)d_in[0];
    const int*   ei    = (const int*)d_in[1];
    const float* prob  = (const float*)d_in[2];
    const float* Wp    = (const float*)d_in[3];
    const float* Wt    = (const float*)d_in[4];
    const float* a_src = (const float*)d_in[5];
    const float* a_trg = (const float*)d_in[6];
    const float* a_tp  = (const float*)d_in[7];
    const float* Wskip = (const float*)d_in[8];
    const float* bias  = (const float*)d_in[9];
    float* out = (float*)d_out;

    const int E = in_sizes[2];        // edge_prob element count = E
    const int* src = ei;              // edge_index row 0
    const int* trg = ei + E;          // edge_index row 1

    // Workspace layout (~35.7 MB)
    float* ws      = (float*)d_ws;
    float* projH   = ws;                          // Nn*HF
    float* s_srcT  = projH  + (size_t)Nn * HF;    // Nn*NH
    float* s_trgT  = s_srcT + (size_t)Nn * NH;    // Nn*NH
    float* ctp     = s_trgT + (size_t)Nn * NH;    // 16
    float* probS   = ctp + 16;                    // E
    int*   srcS    = (int*)(probS + E);           // E
    int*   deg     = srcS + E;                    // Nn
    int*   pos     = deg + Nn;                    // Nn
    int*   partial = pos + Nn;                    // NSCAN (pad 256)
    int*   base    = partial + 256;               // NSCAN (pad 256)

    hipMemsetAsync(deg, 0, (size_t)Nn * sizeof(int), stream);
    k_ctp<<<1, 64, 0, stream>>>(Wt, a_tp, ctp);
    k_count<<<(E + 255) / 256, 256, 0, stream>>>(trg, deg, E);
    k_scan1<<<NSCAN, 256, 0, stream>>>(deg, partial);
    k_scan2<<<1, 256, 0, stream>>>(partial, base);
    k_scan3<<<NSCAN, 256, 0, stream>>>(deg, base, pos);
    k_fill<<<(E + 255) / 256, 256, 0, stream>>>(src, trg, prob, pos, srcS, probS, E);
    k_node<<<Nn / 8, 128, 0, stream>>>(x, Wp, Wskip, a_src, a_trg, bias,
                                       projH, out, s_srcT, s_trgT);
    k_gather<<<NH * NBLK_PER_HEAD, 256, 0, stream>>>(srcS, probS, pos,
                                                     s_srcT, s_trgT, ctp,
                                                     projH, out);
}

// Round 4
// 362.950 us; speedup vs baseline: 2.2362x; 1.1755x over previous
//
#include <hip/hip_runtime.h>
#include <hip/hip_fp16.h>
#include <math.h>

// Problem constants (from reference)
constexpr int Nn  = 50000;   // nodes
constexpr int FIN = 128;     // input features
constexpr int NH  = 8;       // heads
constexpr int FO  = 16;      // features per head
constexpr int HF  = 128;     // NH*FO
constexpr int NBLK_PER_HEAD = (Nn + 3) / 4;     // 12500 (4 nodes / 256-thr block)
constexpr int NSCAN = (Nn + 255) / 256;         // 196 scan blocks

// ---------------------------------------------------------------------------
// init: deg = 0 everywhere; block 0 also computes ctp[h] = <Wt[h,:], a_tp[h,:]>
// ---------------------------------------------------------------------------
__global__ __launch_bounds__(256) void k_init(const float* __restrict__ Wt,
                                              const float* __restrict__ a_tp,
                                              float* __restrict__ ctp,
                                              int* __restrict__ deg)
{
    int i = blockIdx.x * 256 + threadIdx.x;
    if (i < Nn) deg[i] = 0;
    if (blockIdx.x == 0 && threadIdx.x < NH) {
        int h = threadIdx.x;
        float s = 0.f;
        #pragma unroll
        for (int f = 0; f < FO; ++f) s += Wt[h * FO + f] * a_tp[h * FO + f];
        ctp[h] = s;
    }
}

// ---------------------------------------------------------------------------
// Per-node projections.
//   projH[h][n][f] = (x @ Wp^T) head-major     (3.2 MB per head slice)
//   out[n][o]      = (x @ Wskip^T) + bias      (pre-activation accumulator)
//   s_srcT[h][n], s_trgT[h][n]                 (head-major score vectors)
// ---------------------------------------------------------------------------
__global__ __launch_bounds__(128) void k_node(
    const float* __restrict__ x,
    const float* __restrict__ Wp, const float* __restrict__ Wskip,
    const float* __restrict__ a_src, const float* __restrict__ a_trg,
    const float* __restrict__ bias,
    float* __restrict__ projH, float* __restrict__ out,
    float* __restrict__ s_srcT, float* __restrict__ s_trgT)
{
    constexpr int NB = 8;
    __shared__ float xs[NB][FIN];
    const int o  = threadIdx.x;        // 0..127
    const int n0 = blockIdx.x * NB;

    #pragma unroll
    for (int i = 0; i < NB; ++i) xs[i][o] = x[(n0 + i) * FIN + o];
    __syncthreads();

    float accP[NB], accS[NB];
    #pragma unroll
    for (int i = 0; i < NB; ++i) { accP[i] = 0.f; accS[i] = 0.f; }

    const float4* Wp4 = reinterpret_cast<const float4*>(Wp)    + o * (FIN / 4);
    const float4* Ws4 = reinterpret_cast<const float4*>(Wskip) + o * (FIN / 4);

    for (int k4 = 0; k4 < FIN / 4; ++k4) {
        float4 wp = Wp4[k4];
        float4 wsv = Ws4[k4];
        int k = k4 * 4;
        #pragma unroll
        for (int i = 0; i < NB; ++i) {
            float x0 = xs[i][k], x1 = xs[i][k + 1], x2 = xs[i][k + 2], x3 = xs[i][k + 3];
            accP[i] += x0 * wp.x + x1 * wp.y + x2 * wp.z + x3 * wp.w;
            accS[i] += x0 * wsv.x + x1 * wsv.y + x2 * wsv.z + x3 * wsv.w;
        }
    }

    const float asrc = a_src[o];   // flat [H][FO]: index h*16+f == o
    const float atrg = a_trg[o];
    const float bo   = bias[o];
    const int h = o >> 4;
    const int f = o & 15;

    #pragma unroll
    for (int i = 0; i < NB; ++i) {
        const int n = n0 + i;
        projH[((size_t)h * Nn + n) * FO + f] = accP[i];
        out[n * HF + o] = accS[i] + bo;
        float vs = accP[i] * asrc;
        float vt = accP[i] * atrg;
        #pragma unroll
        for (int m = 8; m >= 1; m >>= 1) {
            vs += __shfl_xor(vs, m, 16);
            vt += __shfl_xor(vt, m, 16);
        }
        if (f == 0) {
            s_srcT[h * Nn + n] = vs;
            s_trgT[h * Nn + n] = vt;
        }
    }
}

// ---------------------------------------------------------------------------
// CSR build (by target): count -> 3-phase scan -> fill (writes packed edges)
// ---------------------------------------------------------------------------
__global__ __launch_bounds__(256) void k_count(const int* __restrict__ trg,
                                               int* __restrict__ deg, int E)
{
    int e4 = blockIdx.x * blockDim.x + threadIdx.x;
    if (e4 * 4 < E) {
        int4 t = reinterpret_cast<const int4*>(trg)[e4];
        atomicAdd(&deg[t.x], 1);
        atomicAdd(&deg[t.y], 1);
        atomicAdd(&deg[t.z], 1);
        atomicAdd(&deg[t.w], 1);
    }
}

__global__ __launch_bounds__(256) void k_scan1(const int* __restrict__ deg,
                                               int* __restrict__ partial)
{
    __shared__ int lds[256];
    int t = threadIdx.x, i = blockIdx.x * 256 + t;
    lds[t] = (i < Nn) ? deg[i] : 0;
    __syncthreads();
    for (int off = 128; off > 0; off >>= 1) {
        if (t < off) lds[t] += lds[t + off];
        __syncthreads();
    }
    if (t == 0) partial[blockIdx.x] = lds[0];
}

__global__ __launch_bounds__(256) void k_scan2(const int* __restrict__ partial,
                                               int* __restrict__ base)
{
    __shared__ int lds[256];
    int t = threadIdx.x;
    int v = (t < NSCAN) ? partial[t] : 0;
    lds[t] = v;
    __syncthreads();
    for (int off = 1; off < 256; off <<= 1) {
        int u = (t >= off) ? lds[t - off] : 0;
        __syncthreads();
        lds[t] += u;
        __syncthreads();
    }
    if (t < NSCAN) base[t] = lds[t] - v;   // exclusive prefix of partials
}

__global__ __launch_bounds__(256) void k_scan3(const int* __restrict__ deg,
                                               const int* __restrict__ base,
                                               int* __restrict__ pos)
{
    __shared__ int lds[256];
    int t = threadIdx.x, i = blockIdx.x * 256 + t;
    int v = (i < Nn) ? deg[i] : 0;
    lds[t] = v;
    __syncthreads();
    for (int off = 1; off < 256; off <<= 1) {
        int u = (t >= off) ? lds[t - off] : 0;
        __syncthreads();
        lds[t] += u;
        __syncthreads();
    }
    if (i < Nn) pos[i] = base[blockIdx.x] + lds[t] - v;   // exclusive prefix
}

// fill: pos[n] bumps exclusive -> inclusive; row n spans
// [ (n ? pos[n-1] : 0), pos[n] ) in epk.  epk = src(16b) | f16(prob)(16b).
__global__ __launch_bounds__(256) void k_fill(
    const int* __restrict__ src, const int* __restrict__ trg,
    const float* __restrict__ prob, int* __restrict__ pos,
    unsigned int* __restrict__ epk, int E)
{
    int e4 = blockIdx.x * blockDim.x + threadIdx.x;
    if (e4 * 4 >= E) return;
    int4   s4 = reinterpret_cast<const int4*>(src)[e4];
    int4   t4 = reinterpret_cast<const int4*>(trg)[e4];
    float4 p4 = reinterpret_cast<const float4*>(prob)[e4];
    int    sv[4] = {s4.x, s4.y, s4.z, s4.w};
    int    tv[4] = {t4.x, t4.y, t4.z, t4.w};
    float  pv[4] = {p4.x, p4.y, p4.z, p4.w};
    #pragma unroll
    for (int i = 0; i < 4; ++i) {
        unsigned int pk = (unsigned int)sv[i] |
            ((unsigned int)__half_as_ushort(__float2half_rn(pv[i])) << 16);
        int slot = atomicAdd(&pos[tv[i]], 1);
        epk[slot] = pk;
    }
}

// ---------------------------------------------------------------------------
// Gather, XCD-pinned heads: h = blockIdx.x & 7 (consecutive blocks round-robin
// XCDs, so each XCD's L2 permanently holds one 3.2 MB projH slice + its
// s_srcT slice). One wave per (node, head); lanes = 4 edge-slots x 16 feats.
// ---------------------------------------------------------------------------
__global__ __launch_bounds__(256) void k_gather(
    const unsigned int* __restrict__ epk, const int* __restrict__ pos,
    const float* __restrict__ s_srcT, const float* __restrict__ s_trgT,
    const float* __restrict__ ctp, const float* __restrict__ projH,
    float* __restrict__ out)
{
    const int bid = blockIdx.x;
    const int h   = bid & 7;                   // XCD-pinned head
    const int nb  = bid >> 3;                  // 0..12499
    const int wv  = threadIdx.x >> 6;
    const int lane = threadIdx.x & 63;
    const int n = nb * 4 + wv;                 // 50000 = 12500*4, always valid
    const int es = lane >> 4;                  // edge slot 0..3
    const int f  = lane & 15;                  // feature 0..15

    const int jb = (n == 0) ? 0 : pos[n - 1];
    const int je = pos[n];
    const float st  = s_trgT[h * Nn + n];
    const float cth = ctp[h];
    const float* __restrict__ psl = projH + (size_t)h * Nn * FO;
    const float* __restrict__ ssl = s_srcT + h * Nn;

    float num = 0.f, den = 0.f;
    int j = jb + es;
    // 2x unrolled: two independent gather chains in flight
    for (; j + 4 < je; j += 8) {
        const unsigned int pk0 = epk[j];
        const unsigned int pk1 = epk[j + 4];
        const int s0 = pk0 & 0xFFFF;
        const int s1 = pk1 & 0xFFFF;
        const float g0 = psl[s0 * FO + f];
        const float g1 = psl[s1 * FO + f];
        const float a0 = ssl[s0];
        const float a1 = ssl[s1];
        const float p0 = __half2float(__ushort_as_half((unsigned short)(pk0 >> 16)));
        const float p1 = __half2float(__ushort_as_half((unsigned short)(pk1 >> 16)));
        float sc0 = a0 + st + cth * p0;
        float sc1 = a1 + st + cth * p1;
        sc0 = sc0 >= 0.f ? sc0 : 0.2f * sc0;
        sc1 = sc1 >= 0.f ? sc1 : 0.2f * sc1;
        const float ev0 = __expf(sc0);
        const float ev1 = __expf(sc1);
        den += ev0 + ev1;
        num += ev0 * g0 + ev1 * g1;
    }
    if (j < je) {
        const unsigned int pk = epk[j];
        const int s = pk & 0xFFFF;
        const float p = __half2float(__ushort_as_half((unsigned short)(pk >> 16)));
        float sc = ssl[s] + st + cth * p;
        sc = sc >= 0.f ? sc : 0.2f * sc;
        const float ev = __expf(sc);
        den += ev;
        num += ev * psl[s * FO + f];
    }

    num += __shfl_xor(num, 16, 64);
    den += __shfl_xor(den, 16, 64);
    num += __shfl_xor(num, 32, 64);
    den += __shfl_xor(den, 32, 64);

    if (es == 0) {
        const int idx = n * HF + h * FO + f;
        float v = out[idx] + num / (den + 1e-16f);   // out holds skip+bias
        out[idx] = v > 0.f ? v : expm1f(v);
    }
}

// ---------------------------------------------------------------------------
extern "C" void kernel_launch(void* const* d_in, const int* in_sizes, int n_in,
                              void* d_out, int out_size, void* d_ws, size_t ws_size,
                              hipStream_t stream)
{
    const float* x     = (const float*)d_in[0];
    const int*   ei    = (const int*)d_in[1];
    const float* prob  = (const float*)d_in[2];
    const float* Wp    = (const float*)d_in[3];
    const float* Wt    = (const float*)d_in[4];
    const float* a_src = (const float*)d_in[5];
    const float* a_trg = (const float*)d_in[6];
    const float* a_tp  = (const float*)d_in[7];
    const float* Wskip = (const float*)d_in[8];
    const float* bias  = (const float*)d_in[9];
    float* out = (float*)d_out;

    const int E = in_sizes[2];        // edge_prob element count = E
    const int* src = ei;              // edge_index row 0
    const int* trg = ei + E;          // edge_index row 1

    // Workspace layout (~33 MB)
    float* ws      = (float*)d_ws;
    float* projH   = ws;                          // Nn*HF
    float* s_srcT  = projH  + (size_t)Nn * HF;    // Nn*NH
    float* s_trgT  = s_srcT + (size_t)Nn * NH;    // Nn*NH
    float* ctp     = s_trgT + (size_t)Nn * NH;    // 16
    unsigned int* epk = (unsigned int*)(ctp + 16);// E
    int*   deg     = (int*)(epk + E);             // Nn
    int*   pos     = deg + Nn;                    // Nn
    int*   partial = pos + Nn;                    // NSCAN (pad 256)
    int*   base    = partial + 256;               // NSCAN (pad 256)

    k_init<<<NSCAN, 256, 0, stream>>>(Wt, a_tp, ctp, deg);
    k_count<<<(E / 4 + 255) / 256, 256, 0, stream>>>(trg, deg, E);
    k_scan1<<<NSCAN, 256, 0, stream>>>(deg, partial);
    k_scan2<<<1, 256, 0, stream>>>(partial, base);
    k_scan3<<<NSCAN, 256, 0, stream>>>(deg, base, pos);
    k_fill<<<(E / 4 + 255) / 256, 256, 0, stream>>>(src, trg, prob, pos, epk, E);
    k_node<<<Nn / 8, 128, 0, stream>>>(x, Wp, Wskip, a_src, a_trg, bias,
                                       projH, out, s_srcT, s_trgT);
    k_gather<<<NH * NBLK_PER_HEAD, 256, 0, stream>>>(epk, pos, s_srcT, s_trgT,
                                                     ctp, projH, out);
}

// Round 5
// 359.850 us; speedup vs baseline: 2.2555x; 1.0086x over previous
//
#include <hip/hip_runtime.h>
#include <hip/hip_fp16.h>
#include <math.h>

// Problem constants (from reference)
constexpr int Nn  = 50000;   // nodes
constexpr int FIN = 128;     // input features
constexpr int NH  = 8;       // heads
constexpr int FO  = 16;      // features per head
constexpr int HF  = 128;     // NH*FO
constexpr int NSCAN = (Nn + 255) / 256;         // 196 scan blocks

// ---------------------------------------------------------------------------
// init: deg = 0 everywhere; block 0 also computes ctp[h] = <Wt[h,:], a_tp[h,:]>
// ---------------------------------------------------------------------------
__global__ __launch_bounds__(256) void k_init(const float* __restrict__ Wt,
                                              const float* __restrict__ a_tp,
                                              float* __restrict__ ctp,
                                              int* __restrict__ deg)
{
    int i = blockIdx.x * 256 + threadIdx.x;
    if (i < Nn) deg[i] = 0;
    if (blockIdx.x == 0 && threadIdx.x < NH) {
        int h = threadIdx.x;
        float s = 0.f;
        #pragma unroll
        for (int f = 0; f < FO; ++f) s += Wt[h * FO + f] * a_tp[h * FO + f];
        ctp[h] = s;
    }
}

// ---------------------------------------------------------------------------
// Per-node projections.
//   projH[h][n][f] = (x @ Wp^T) head-major     (3.2 MB per head slice)
//   out[n][o]      = (x @ Wskip^T) + bias      (pre-activation accumulator)
//   s_pair[n][0..7]  = src scores per head
//   s_pair[n][8..15] = trg scores per head     (64 B per node, L2-friendly)
// ---------------------------------------------------------------------------
__global__ __launch_bounds__(128) void k_node(
    const float* __restrict__ x,
    const float* __restrict__ Wp, const float* __restrict__ Wskip,
    const float* __restrict__ a_src, const float* __restrict__ a_trg,
    const float* __restrict__ bias,
    float* __restrict__ projH, float* __restrict__ out,
    float* __restrict__ s_pair)
{
    constexpr int NB = 8;
    __shared__ float xs[NB][FIN];
    const int o  = threadIdx.x;        // 0..127
    const int n0 = blockIdx.x * NB;

    #pragma unroll
    for (int i = 0; i < NB; ++i) xs[i][o] = x[(n0 + i) * FIN + o];
    __syncthreads();

    float accP[NB], accS[NB];
    #pragma unroll
    for (int i = 0; i < NB; ++i) { accP[i] = 0.f; accS[i] = 0.f; }

    const float4* Wp4 = reinterpret_cast<const float4*>(Wp)    + o * (FIN / 4);
    const float4* Ws4 = reinterpret_cast<const float4*>(Wskip) + o * (FIN / 4);

    for (int k4 = 0; k4 < FIN / 4; ++k4) {
        float4 wp = Wp4[k4];
        float4 wsv = Ws4[k4];
        int k = k4 * 4;
        #pragma unroll
        for (int i = 0; i < NB; ++i) {
            float x0 = xs[i][k], x1 = xs[i][k + 1], x2 = xs[i][k + 2], x3 = xs[i][k + 3];
            accP[i] += x0 * wp.x + x1 * wp.y + x2 * wp.z + x3 * wp.w;
            accS[i] += x0 * wsv.x + x1 * wsv.y + x2 * wsv.z + x3 * wsv.w;
        }
    }

    const float asrc = a_src[o];   // flat [H][FO]: index h*16+f == o
    const float atrg = a_trg[o];
    const float bo   = bias[o];
    const int h = o >> 4;
    const int f = o & 15;

    #pragma unroll
    for (int i = 0; i < NB; ++i) {
        const int n = n0 + i;
        projH[((size_t)h * Nn + n) * FO + f] = accP[i];
        out[n * HF + o] = accS[i] + bo;
        float vs = accP[i] * asrc;
        float vt = accP[i] * atrg;
        #pragma unroll
        for (int m = 8; m >= 1; m >>= 1) {
            vs += __shfl_xor(vs, m, 16);
            vt += __shfl_xor(vt, m, 16);
        }
        if (f == 0) {
            s_pair[n * 16 + h]     = vs;
            s_pair[n * 16 + 8 + h] = vt;
        }
    }
}

// ---------------------------------------------------------------------------
// CSR build (by target): count -> 3-phase scan -> fill (packed sorted edges)
// ---------------------------------------------------------------------------
__global__ __launch_bounds__(256) void k_count(const int* __restrict__ trg,
                                               int* __restrict__ deg, int E)
{
    int e4 = blockIdx.x * blockDim.x + threadIdx.x;
    if (e4 * 4 < E) {
        int4 t = reinterpret_cast<const int4*>(trg)[e4];
        atomicAdd(&deg[t.x], 1);
        atomicAdd(&deg[t.y], 1);
        atomicAdd(&deg[t.z], 1);
        atomicAdd(&deg[t.w], 1);
    }
}

__global__ __launch_bounds__(256) void k_scan1(const int* __restrict__ deg,
                                               int* __restrict__ partial)
{
    __shared__ int lds[256];
    int t = threadIdx.x, i = blockIdx.x * 256 + t;
    lds[t] = (i < Nn) ? deg[i] : 0;
    __syncthreads();
    for (int off = 128; off > 0; off >>= 1) {
        if (t < off) lds[t] += lds[t + off];
        __syncthreads();
    }
    if (t == 0) partial[blockIdx.x] = lds[0];
}

__global__ __launch_bounds__(256) void k_scan2(const int* __restrict__ partial,
                                               int* __restrict__ base)
{
    __shared__ int lds[256];
    int t = threadIdx.x;
    int v = (t < NSCAN) ? partial[t] : 0;
    lds[t] = v;
    __syncthreads();
    for (int off = 1; off < 256; off <<= 1) {
        int u = (t >= off) ? lds[t - off] : 0;
        __syncthreads();
        lds[t] += u;
        __syncthreads();
    }
    if (t < NSCAN) base[t] = lds[t] - v;   // exclusive prefix of partials
}

__global__ __launch_bounds__(256) void k_scan3(const int* __restrict__ deg,
                                               const int* __restrict__ base,
                                               int* __restrict__ pos)
{
    __shared__ int lds[256];
    int t = threadIdx.x, i = blockIdx.x * 256 + t;
    int v = (i < Nn) ? deg[i] : 0;
    lds[t] = v;
    __syncthreads();
    for (int off = 1; off < 256; off <<= 1) {
        int u = (t >= off) ? lds[t - off] : 0;
        __syncthreads();
        lds[t] += u;
        __syncthreads();
    }
    if (i < Nn) pos[i] = base[blockIdx.x] + lds[t] - v;   // exclusive prefix
}

// fill: pos[n] bumps exclusive -> inclusive; row n spans
// [ (n ? pos[n-1] : 0), pos[n] ).  epk = src(16b) | trg(16b); pkp = f16(prob).
__global__ __launch_bounds__(256) void k_fill(
    const int* __restrict__ src, const int* __restrict__ trg,
    const float* __restrict__ prob, int* __restrict__ pos,
    unsigned int* __restrict__ epk, __half* __restrict__ pkp, int E)
{
    int e4 = blockIdx.x * blockDim.x + threadIdx.x;
    if (e4 * 4 >= E) return;
    int4   s4 = reinterpret_cast<const int4*>(src)[e4];
    int4   t4 = reinterpret_cast<const int4*>(trg)[e4];
    float4 p4 = reinterpret_cast<const float4*>(prob)[e4];
    int    sv[4] = {s4.x, s4.y, s4.z, s4.w};
    int    tv[4] = {t4.x, t4.y, t4.z, t4.w};
    float  pv[4] = {p4.x, p4.y, p4.z, p4.w};
    #pragma unroll
    for (int i = 0; i < 4; ++i) {
        int slot = atomicAdd(&pos[tv[i]], 1);
        epk[slot] = (unsigned int)sv[i] | ((unsigned int)tv[i] << 16);
        pkp[slot] = __float2half_rn(pv[i]);
    }
}

// ---------------------------------------------------------------------------
// Edge-weight precompute: for each sorted slot e, compute exp(leaky(score))
// for all 8 heads; pack (src | f16(ev) << 16) head-major: ewk[h][e].
// One thread per edge, no redundancy; scores from L2-resident s_pair.
// ---------------------------------------------------------------------------
__global__ __launch_bounds__(256) void k_ev(
    const unsigned int* __restrict__ epk, const __half* __restrict__ pkp,
    const float* __restrict__ s_pair, const float* __restrict__ ctp,
    unsigned int* __restrict__ ewk, int E)
{
    int e = blockIdx.x * 256 + threadIdx.x;
    if (e >= E) return;
    const unsigned int pk = epk[e];
    const int s = pk & 0xFFFF;
    const int t = pk >> 16;
    const float p = __half2float(pkp[e]);

    const float4* sp = reinterpret_cast<const float4*>(s_pair);
    float4 ss0 = sp[s * 4 + 0];
    float4 ss1 = sp[s * 4 + 1];
    float4 st0 = sp[t * 4 + 2];
    float4 st1 = sp[t * 4 + 3];
    float ssv[8] = {ss0.x, ss0.y, ss0.z, ss0.w, ss1.x, ss1.y, ss1.z, ss1.w};
    float stv[8] = {st0.x, st0.y, st0.z, st0.w, st1.x, st1.y, st1.z, st1.w};

    #pragma unroll
    for (int h = 0; h < NH; ++h) {
        float sc = ssv[h] + stv[h] + ctp[h] * p;
        sc = sc >= 0.f ? sc : 0.2f * sc;
        float ev = __expf(sc);
        ewk[(size_t)h * E + e] = (unsigned int)s |
            ((unsigned int)__half_as_ushort(__float2half_rn(ev)) << 16);
    }
}

// ---------------------------------------------------------------------------
// Gather, XCD-pinned heads (h = blockIdx.x & 7). One wave per (node, head);
// lanes = 4 edge-slots x 16 features. Inner loop: one 4B broadcast (ewk) +
// one 4B gather (projH) + 2 FMA per edge. No exp, no score work.
// ---------------------------------------------------------------------------
__global__ __launch_bounds__(256) void k_gather(
    const unsigned int* __restrict__ ewk, const int* __restrict__ pos,
    const float* __restrict__ projH, float* __restrict__ out, int E)
{
    const int bid = blockIdx.x;
    const int h   = bid & 7;                   // XCD-pinned head
    const int nb  = bid >> 3;                  // 0..12499
    const int wv  = threadIdx.x >> 6;
    const int lane = threadIdx.x & 63;
    const int n = nb * 4 + wv;                 // 50000 = 12500*4, always valid
    const int es = lane >> 4;                  // edge slot 0..3
    const int f  = lane & 15;                  // feature 0..15

    const int jb = (n == 0) ? 0 : pos[n - 1];
    const int je = pos[n];
    const unsigned int* __restrict__ ew = ewk + (size_t)h * E;
    const float* __restrict__ psl = projH + (size_t)h * Nn * FO;

    float num = 0.f, den = 0.f;
    int j = jb + es;
    // 2x unrolled: two independent gather chains in flight
    for (; j + 4 < je; j += 8) {
        const unsigned int u0 = ew[j];
        const unsigned int u1 = ew[j + 4];
        const int s0 = u0 & 0xFFFF;
        const int s1 = u1 & 0xFFFF;
        const float ev0 = __half2float(__ushort_as_half((unsigned short)(u0 >> 16)));
        const float ev1 = __half2float(__ushort_as_half((unsigned short)(u1 >> 16)));
        const float g0 = psl[s0 * FO + f];
        const float g1 = psl[s1 * FO + f];
        den += ev0 + ev1;
        num += ev0 * g0 + ev1 * g1;
    }
    if (j < je) {
        const unsigned int u = ew[j];
        const int s = u & 0xFFFF;
        const float ev = __half2float(__ushort_as_half((unsigned short)(u >> 16)));
        den += ev;
        num += ev * psl[s * FO + f];
    }

    num += __shfl_xor(num, 16, 64);
    den += __shfl_xor(den, 16, 64);
    num += __shfl_xor(num, 32, 64);
    den += __shfl_xor(den, 32, 64);

    if (es == 0) {
        const int idx = n * HF + h * FO + f;
        float v = out[idx] + num / (den + 1e-16f);   // out holds skip+bias
        out[idx] = v > 0.f ? v : expm1f(v);
    }
}

// ---------------------------------------------------------------------------
extern "C" void kernel_launch(void* const* d_in, const int* in_sizes, int n_in,
                              void* d_out, int out_size, void* d_ws, size_t ws_size,
                              hipStream_t stream)
{
    const float* x     = (const float*)d_in[0];
    const int*   ei    = (const int*)d_in[1];
    const float* prob  = (const float*)d_in[2];
    const float* Wp    = (const float*)d_in[3];
    const float* Wt    = (const float*)d_in[4];
    const float* a_src = (const float*)d_in[5];
    const float* a_trg = (const float*)d_in[6];
    const float* a_tp  = (const float*)d_in[7];
    const float* Wskip = (const float*)d_in[8];
    const float* bias  = (const float*)d_in[9];
    float* out = (float*)d_out;

    const int E = in_sizes[2];        // edge_prob element count = E
    const int* src = ei;              // edge_index row 0
    const int* trg = ei + E;          // edge_index row 1

    // Workspace layout (~60 MB)
    float* ws      = (float*)d_ws;
    float* projH   = ws;                          // Nn*HF        (25.6 MB)
    float* s_pair  = projH  + (size_t)Nn * HF;    // Nn*16        (3.2 MB)
    float* ctp     = s_pair + (size_t)Nn * 16;    // 16
    unsigned int* epk = (unsigned int*)(ctp + 16);// E            (3.2 MB)
    __half* pkp    = (__half*)(epk + E);          // E            (1.6 MB)
    unsigned int* ewk = (unsigned int*)(pkp + E); // NH*E         (25.6 MB)
    int*   deg     = (int*)(ewk + (size_t)NH * E);// Nn
    int*   pos     = deg + Nn;                    // Nn
    int*   partial = pos + Nn;                    // NSCAN (pad 256)
    int*   base    = partial + 256;               // NSCAN (pad 256)

    k_init<<<NSCAN, 256, 0, stream>>>(Wt, a_tp, ctp, deg);
    k_count<<<(E / 4 + 255) / 256, 256, 0, stream>>>(trg, deg, E);
    k_scan1<<<NSCAN, 256, 0, stream>>>(deg, partial);
    k_scan2<<<1, 256, 0, stream>>>(partial, base);
    k_scan3<<<NSCAN, 256, 0, stream>>>(deg, base, pos);
    k_fill<<<(E / 4 + 255) / 256, 256, 0, stream>>>(src, trg, prob, pos,
                                                    epk, pkp, E);
    k_node<<<Nn / 8, 128, 0, stream>>>(x, Wp, Wskip, a_src, a_trg, bias,
                                       projH, out, s_pair);
    k_ev<<<(E + 255) / 256, 256, 0, stream>>>(epk, pkp, s_pair, ctp, ewk, E);
    k_gather<<<NH * (Nn / 4), 256, 0, stream>>>(ewk, pos, projH, out, E);
}

// Round 6
// 351.149 us; speedup vs baseline: 2.3113x; 1.0248x over previous
//
#include <hip/hip_runtime.h>
#include <hip/hip_fp16.h>
#include <math.h>

// Problem constants (from reference)
constexpr int Nn  = 50000;   // nodes
constexpr int FIN = 128;     // input features
constexpr int NH  = 8;       // heads
constexpr int FO  = 16;      // features per head
constexpr int HF  = 128;     // NH*FO
constexpr int NSCAN = (Nn + 255) / 256;         // 196 scan blocks

// ---------------------------------------------------------------------------
// CSR count (by target); block 0 also computes ctp[h] = <Wt[h,:], a_tp[h,:]>
// ---------------------------------------------------------------------------
__global__ __launch_bounds__(256) void k_count(const int* __restrict__ trg,
                                               int* __restrict__ deg,
                                               const float* __restrict__ Wt,
                                               const float* __restrict__ a_tp,
                                               float* __restrict__ ctp, int E)
{
    if (blockIdx.x == 0 && threadIdx.x < NH) {
        int h = threadIdx.x;
        float s = 0.f;
        #pragma unroll
        for (int f = 0; f < FO; ++f) s += Wt[h * FO + f] * a_tp[h * FO + f];
        ctp[h] = s;
    }
    int e4 = blockIdx.x * blockDim.x + threadIdx.x;
    if (e4 * 4 < E) {
        int4 t = reinterpret_cast<const int4*>(trg)[e4];
        atomicAdd(&deg[t.x], 1);
        atomicAdd(&deg[t.y], 1);
        atomicAdd(&deg[t.z], 1);
        atomicAdd(&deg[t.w], 1);
    }
}

// ---------------------------------------------------------------------------
// Per-node projections.
//   projH[h][n][f] = (x @ Wp^T) head-major, fp16   (1.6 MB per head slice)
//   out[n][o]      = (x @ Wskip^T) + bias          (pre-activation accumulator)
//   s_pair[n][0..7]=src scores, [8..15]=trg scores (64 B per node)
// ---------------------------------------------------------------------------
__global__ __launch_bounds__(128) void k_node(
    const float* __restrict__ x,
    const float* __restrict__ Wp, const float* __restrict__ Wskip,
    const float* __restrict__ a_src, const float* __restrict__ a_trg,
    const float* __restrict__ bias,
    __half* __restrict__ projH, float* __restrict__ out,
    float* __restrict__ s_pair)
{
    constexpr int NB = 8;
    __shared__ float xs[NB][FIN];
    const int o  = threadIdx.x;        // 0..127
    const int n0 = blockIdx.x * NB;

    #pragma unroll
    for (int i = 0; i < NB; ++i) xs[i][o] = x[(n0 + i) * FIN + o];
    __syncthreads();

    float accP[NB], accS[NB];
    #pragma unroll
    for (int i = 0; i < NB; ++i) { accP[i] = 0.f; accS[i] = 0.f; }

    const float4* Wp4 = reinterpret_cast<const float4*>(Wp)    + o * (FIN / 4);
    const float4* Ws4 = reinterpret_cast<const float4*>(Wskip) + o * (FIN / 4);

    for (int k4 = 0; k4 < FIN / 4; ++k4) {
        float4 wp = Wp4[k4];
        float4 wsv = Ws4[k4];
        int k = k4 * 4;
        #pragma unroll
        for (int i = 0; i < NB; ++i) {
            float x0 = xs[i][k], x1 = xs[i][k + 1], x2 = xs[i][k + 2], x3 = xs[i][k + 3];
            accP[i] += x0 * wp.x + x1 * wp.y + x2 * wp.z + x3 * wp.w;
            accS[i] += x0 * wsv.x + x1 * wsv.y + x2 * wsv.z + x3 * wsv.w;
        }
    }

    const float asrc = a_src[o];   // flat [H][FO]: index h*16+f == o
    const float atrg = a_trg[o];
    const float bo   = bias[o];
    const int h = o >> 4;
    const int f = o & 15;

    #pragma unroll
    for (int i = 0; i < NB; ++i) {
        const int n = n0 + i;
        projH[((size_t)h * Nn + n) * FO + f] = __float2half_rn(accP[i]);
        out[n * HF + o] = accS[i] + bo;
        float vs = accP[i] * asrc;
        float vt = accP[i] * atrg;
        #pragma unroll
        for (int m = 8; m >= 1; m >>= 1) {
            vs += __shfl_xor(vs, m, 16);
            vt += __shfl_xor(vt, m, 16);
        }
        if (f == 0) {
            s_pair[n * 16 + h]     = vs;
            s_pair[n * 16 + 8 + h] = vt;
        }
    }
}

// ---------------------------------------------------------------------------
// 3-phase exclusive scan of deg -> pos
// ---------------------------------------------------------------------------
__global__ __launch_bounds__(256) void k_scan1(const int* __restrict__ deg,
                                               int* __restrict__ partial)
{
    __shared__ int lds[256];
    int t = threadIdx.x, i = blockIdx.x * 256 + t;
    lds[t] = (i < Nn) ? deg[i] : 0;
    __syncthreads();
    for (int off = 128; off > 0; off >>= 1) {
        if (t < off) lds[t] += lds[t + off];
        __syncthreads();
    }
    if (t == 0) partial[blockIdx.x] = lds[0];
}

__global__ __launch_bounds__(256) void k_scan2(const int* __restrict__ partial,
                                               int* __restrict__ base)
{
    __shared__ int lds[256];
    int t = threadIdx.x;
    int v = (t < NSCAN) ? partial[t] : 0;
    lds[t] = v;
    __syncthreads();
    for (int off = 1; off < 256; off <<= 1) {
        int u = (t >= off) ? lds[t - off] : 0;
        __syncthreads();
        lds[t] += u;
        __syncthreads();
    }
    if (t < NSCAN) base[t] = lds[t] - v;   // exclusive prefix of partials
}

__global__ __launch_bounds__(256) void k_scan3(const int* __restrict__ deg,
                                               const int* __restrict__ base,
                                               int* __restrict__ pos)
{
    __shared__ int lds[256];
    int t = threadIdx.x, i = blockIdx.x * 256 + t;
    int v = (i < Nn) ? deg[i] : 0;
    lds[t] = v;
    __syncthreads();
    for (int off = 1; off < 256; off <<= 1) {
        int u = (t >= off) ? lds[t - off] : 0;
        __syncthreads();
        lds[t] += u;
        __syncthreads();
    }
    if (i < Nn) pos[i] = base[blockIdx.x] + lds[t] - v;   // exclusive prefix
}

// fill: pos[n] bumps exclusive -> inclusive; row n spans
// [ (n ? pos[n-1] : 0), pos[n] ).  epk2 = { src|trg<<16, f16(prob) }  (8B)
__global__ __launch_bounds__(256) void k_fill(
    const int* __restrict__ src, const int* __restrict__ trg,
    const float* __restrict__ prob, int* __restrict__ pos,
    uint2* __restrict__ epk2, int E)
{
    int e4 = blockIdx.x * blockDim.x + threadIdx.x;
    if (e4 * 4 >= E) return;
    int4   s4 = reinterpret_cast<const int4*>(src)[e4];
    int4   t4 = reinterpret_cast<const int4*>(trg)[e4];
    float4 p4 = reinterpret_cast<const float4*>(prob)[e4];
    int    sv[4] = {s4.x, s4.y, s4.z, s4.w};
    int    tv[4] = {t4.x, t4.y, t4.z, t4.w};
    float  pv[4] = {p4.x, p4.y, p4.z, p4.w};
    #pragma unroll
    for (int i = 0; i < 4; ++i) {
        int slot = atomicAdd(&pos[tv[i]], 1);
        uint2 pk;
        pk.x = (unsigned int)sv[i] | ((unsigned int)tv[i] << 16);
        pk.y = (unsigned int)__half_as_ushort(__float2half_rn(pv[i]));
        epk2[slot] = pk;
    }
}

// ---------------------------------------------------------------------------
// Edge-weight precompute: for each sorted slot e, exp(leaky(score)) for all
// 8 heads; pack (src | f16(ev) << 16) head-major: ewk[h][e].
// ---------------------------------------------------------------------------
__global__ __launch_bounds__(256) void k_ev(
    const uint2* __restrict__ epk2,
    const float* __restrict__ s_pair, const float* __restrict__ ctp,
    unsigned int* __restrict__ ewk, int E)
{
    int e = blockIdx.x * 256 + threadIdx.x;
    if (e >= E) return;
    const uint2 pk = epk2[e];
    const int s = pk.x & 0xFFFF;
    const int t = pk.x >> 16;
    const float p = __half2float(__ushort_as_half((unsigned short)pk.y));

    const float4* sp = reinterpret_cast<const float4*>(s_pair);
    float4 ss0 = sp[s * 4 + 0];
    float4 ss1 = sp[s * 4 + 1];
    float4 st0 = sp[t * 4 + 2];
    float4 st1 = sp[t * 4 + 3];
    float ssv[8] = {ss0.x, ss0.y, ss0.z, ss0.w, ss1.x, ss1.y, ss1.z, ss1.w};
    float stv[8] = {st0.x, st0.y, st0.z, st0.w, st1.x, st1.y, st1.z, st1.w};

    #pragma unroll
    for (int h = 0; h < NH; ++h) {
        float sc = ssv[h] + stv[h] + ctp[h] * p;
        sc = sc >= 0.f ? sc : 0.2f * sc;
        float ev = __expf(sc);
        ewk[(size_t)h * E + e] = (unsigned int)s |
            ((unsigned int)__half_as_ushort(__float2half_rn(ev)) << 16);
    }
}

// ---------------------------------------------------------------------------
// Gather, XCD-pinned heads (h = blockIdx.x & 7). One wave per (node, head);
// lanes = 8 edge-slots x 8 feature-pairs (half2 proj). Inner loop per edge:
// one 4B broadcast (ewk) + one 4B half2 gather + 3 FMA.
// ---------------------------------------------------------------------------
__global__ __launch_bounds__(256) void k_gather(
    const unsigned int* __restrict__ ewk, const int* __restrict__ pos,
    const __half2* __restrict__ projH, float* __restrict__ out, int E)
{
    const int bid = blockIdx.x;
    const int h   = bid & 7;                   // XCD-pinned head
    const int nb  = bid >> 3;                  // 0..12499
    const int wv  = threadIdx.x >> 6;
    const int lane = threadIdx.x & 63;
    const int n = nb * 4 + wv;                 // 50000 = 12500*4, always valid
    const int es = lane >> 3;                  // edge slot 0..7
    const int f2 = lane & 7;                   // feature pair 0..7

    const int jb = (n == 0) ? 0 : pos[n - 1];
    const int je = pos[n];
    const unsigned int* __restrict__ ew = ewk + (size_t)h * E;
    const __half2* __restrict__ psl = projH + (size_t)h * Nn * (FO / 2);

    float num0 = 0.f, num1 = 0.f, den = 0.f;
    int j = jb + es;
    // 2x unrolled: two independent gather chains in flight
    for (; j + 8 < je; j += 16) {
        const unsigned int u0 = ew[j];
        const unsigned int u1 = ew[j + 8];
        const int s0 = u0 & 0xFFFF;
        const int s1 = u1 & 0xFFFF;
        const __half2 g0 = psl[s0 * (FO / 2) + f2];
        const __half2 g1 = psl[s1 * (FO / 2) + f2];
        const float ev0 = __half2float(__ushort_as_half((unsigned short)(u0 >> 16)));
        const float ev1 = __half2float(__ushort_as_half((unsigned short)(u1 >> 16)));
        const float2 G0 = __half22float2(g0);
        const float2 G1 = __half22float2(g1);
        den  += ev0 + ev1;
        num0 += ev0 * G0.x + ev1 * G1.x;
        num1 += ev0 * G0.y + ev1 * G1.y;
    }
    if (j < je) {
        const unsigned int u = ew[j];
        const int s = u & 0xFFFF;
        const float ev = __half2float(__ushort_as_half((unsigned short)(u >> 16)));
        const float2 G = __half22float2(psl[s * (FO / 2) + f2]);
        den  += ev;
        num0 += ev * G.x;
        num1 += ev * G.y;
    }

    #pragma unroll
    for (int m = 8; m <= 32; m <<= 1) {
        num0 += __shfl_xor(num0, m, 64);
        num1 += __shfl_xor(num1, m, 64);
        den  += __shfl_xor(den,  m, 64);
    }

    if (es == 0) {
        const int idx = n * HF + h * FO + f2 * 2;
        const float inv = 1.f / (den + 1e-16f);
        float2 o = *reinterpret_cast<float2*>(&out[idx]);  // skip+bias
        float v0 = o.x + num0 * inv;
        float v1 = o.y + num1 * inv;
        v0 = v0 > 0.f ? v0 : expm1f(v0);
        v1 = v1 > 0.f ? v1 : expm1f(v1);
        *reinterpret_cast<float2*>(&out[idx]) = make_float2(v0, v1);
    }
}

// ---------------------------------------------------------------------------
extern "C" void kernel_launch(void* const* d_in, const int* in_sizes, int n_in,
                              void* d_out, int out_size, void* d_ws, size_t ws_size,
                              hipStream_t stream)
{
    const float* x     = (const float*)d_in[0];
    const int*   ei    = (const int*)d_in[1];
    const float* prob  = (const float*)d_in[2];
    const float* Wp    = (const float*)d_in[3];
    const float* Wt    = (const float*)d_in[4];
    const float* a_src = (const float*)d_in[5];
    const float* a_trg = (const float*)d_in[6];
    const float* a_tp  = (const float*)d_in[7];
    const float* Wskip = (const float*)d_in[8];
    const float* bias  = (const float*)d_in[9];
    float* out = (float*)d_out;

    const int E = in_sizes[2];        // edge_prob element count = E
    const int* src = ei;              // edge_index row 0
    const int* trg = ei + E;          // edge_index row 1

    // Workspace layout (~48.5 MB)
    char* wsb = (char*)d_ws;
    __half* projH  = (__half*)wsb;                      // Nn*HF f16 (12.8 MB)
    float* s_pair  = (float*)(wsb + (size_t)Nn*HF*2);   // Nn*16     (3.2 MB)
    float* ctp     = s_pair + (size_t)Nn * 16;          // 16
    uint2* epk2    = (uint2*)(ctp + 16);                // E         (6.4 MB)
    unsigned int* ewk = (unsigned int*)(epk2 + E);      // NH*E      (25.6 MB)
    int*   deg     = (int*)(ewk + (size_t)NH * E);      // Nn
    int*   pos     = deg + Nn;                          // Nn
    int*   partial = pos + Nn;                          // NSCAN (pad 256)
    int*   base    = partial + 256;                     // NSCAN (pad 256)

    hipMemsetAsync(deg, 0, (size_t)Nn * sizeof(int), stream);
    k_count<<<(E / 4 + 255) / 256, 256, 0, stream>>>(trg, deg, Wt, a_tp, ctp, E);
    k_scan1<<<NSCAN, 256, 0, stream>>>(deg, partial);
    k_scan2<<<1, 256, 0, stream>>>(partial, base);
    k_scan3<<<NSCAN, 256, 0, stream>>>(deg, base, pos);
    k_fill<<<(E / 4 + 255) / 256, 256, 0, stream>>>(src, trg, prob, pos, epk2, E);
    k_node<<<Nn / 8, 128, 0, stream>>>(x, Wp, Wskip, a_src, a_trg, bias,
                                       projH, out, s_pair);
    k_ev<<<(E + 255) / 256, 256, 0, stream>>>(epk2, s_pair, ctp, ewk, E);
    k_gather<<<NH * (Nn / 4), 256, 0, stream>>>(ewk, pos,
                                                (const __half2*)projH, out, E);
}

// Round 7
// 281.890 us; speedup vs baseline: 2.8792x; 1.2457x over previous
//
#include <hip/hip_runtime.h>
#include <hip/hip_fp16.h>
#include <math.h>

// Problem constants (from reference)
constexpr int Nn  = 50000;   // nodes
constexpr int FIN = 128;     // input features
constexpr int NH  = 8;       // heads
constexpr int FO  = 16;      // features per head
constexpr int HF  = 128;     // NH*FO
constexpr int NWR = 272;     // Wh rows: Wp(128) | Wskip(128) | Va_src(8) | Va_trg(8)
constexpr int NSCAN = (Nn + 255) / 256;         // 196 scan blocks

typedef _Float16 f16x8 __attribute__((ext_vector_type(8)));
typedef float    f32x4 __attribute__((ext_vector_type(4)));

// ---------------------------------------------------------------------------
// Weight prep: Wh[272][128] f16 =
//   rows   0..127 : Wp
//   rows 128..255 : Wskip
//   rows 256..263 : Va_src[h][k] = sum_f a_src[h,f] * Wp[h*16+f][k]
//   rows 264..271 : Va_trg[h][k] = sum_f a_trg[h,f] * Wp[h*16+f][k]
// (scores become extra GEMM columns: s_src[n,h] = x[n] . Va_src[h])
// ---------------------------------------------------------------------------
__global__ __launch_bounds__(128) void k_prep(
    const float* __restrict__ Wp, const float* __restrict__ Wskip,
    const float* __restrict__ a_src, const float* __restrict__ a_trg,
    _Float16* __restrict__ Wh)
{
    const int o = blockIdx.x;   // 0..271
    const int k = threadIdx.x;  // 0..127
    float v;
    if (o < 128)      v = Wp[o * FIN + k];
    else if (o < 256) v = Wskip[(o - 128) * FIN + k];
    else if (o < 264) {
        const int h = o - 256;
        float s = 0.f;
        #pragma unroll
        for (int f = 0; f < FO; ++f)
            s += a_src[h * FO + f] * Wp[(h * FO + f) * FIN + k];
        v = s;
    } else {
        const int h = o - 264;
        float s = 0.f;
        #pragma unroll
        for (int f = 0; f < FO; ++f)
            s += a_trg[h * FO + f] * Wp[(h * FO + f) * FIN + k];
        v = s;
    }
    Wh[o * FIN + k] = (_Float16)v;
}

// ---------------------------------------------------------------------------
// Node GEMM via MFMA f16: one wave per 16-node stripe, C = x @ Wh^T
// (50000 x 272). 17 N-tiles x 4 K-steps = 68 mfma_f32_16x16x32_f16.
// Epilogue scatters: projH (f16, head-major), out = skip + bias, s_pair.
// A-frag: row = lane&15, k = (lane>>4)*8 + j   (8 contiguous x floats -> f16)
// B-frag: col = lane&15, k = (lane>>4)*8 + j   (16B load from Wh row)
// D-frag: col = lane&15, row = (lane>>4)*4 + r
// ---------------------------------------------------------------------------
__global__ __launch_bounds__(64) void k_node(
    const float* __restrict__ x, const _Float16* __restrict__ Wh,
    const float* __restrict__ bias,
    __half* __restrict__ projH, float* __restrict__ out,
    float* __restrict__ s_pair)
{
    const int n0 = blockIdx.x * 16;            // 3125 * 16 = 50000 exactly
    const int l  = threadIdx.x;                // 0..63
    const int lr = l & 15;
    const int kb = l >> 4;                     // k-block 0..3

    // A fragments for all 4 K-steps (x row in registers, cvt to f16)
    f16x8 a[4];
    const float* xr = x + (size_t)(n0 + lr) * FIN + kb * 8;
    #pragma unroll
    for (int ks = 0; ks < 4; ++ks) {
        float4 u0 = *reinterpret_cast<const float4*>(xr + ks * 32);
        float4 u1 = *reinterpret_cast<const float4*>(xr + ks * 32 + 4);
        a[ks][0] = (_Float16)u0.x; a[ks][1] = (_Float16)u0.y;
        a[ks][2] = (_Float16)u0.z; a[ks][3] = (_Float16)u0.w;
        a[ks][4] = (_Float16)u1.x; a[ks][5] = (_Float16)u1.y;
        a[ks][6] = (_Float16)u1.z; a[ks][7] = (_Float16)u1.w;
    }

    f32x4 acc[17];
    #pragma unroll
    for (int t = 0; t < 17; ++t) acc[t] = (f32x4){0.f, 0.f, 0.f, 0.f};

    const _Float16* wb = Wh + (size_t)lr * FIN + kb * 8;
    #pragma unroll
    for (int t = 0; t < 17; ++t) {
        const _Float16* wt = wb + (size_t)t * 16 * FIN;
        #pragma unroll
        for (int ks = 0; ks < 4; ++ks) {
            f16x8 b = *reinterpret_cast<const f16x8*>(wt + ks * 32);
            acc[t] = __builtin_amdgcn_mfma_f32_16x16x32_f16(a[ks], b, acc[t], 0, 0, 0);
        }
    }

    #pragma unroll
    for (int r = 0; r < 4; ++r) {
        const int n = n0 + kb * 4 + r;
        // proj heads (tiles 0..7), head-major f16
        #pragma unroll
        for (int t = 0; t < 8; ++t)
            projH[((size_t)t * Nn + n) * FO + lr] = __float2half_rn(acc[t][r]);
        // skip + bias (tiles 8..15) -> output accumulator
        #pragma unroll
        for (int t = 8; t < 16; ++t) {
            const int o = (t - 8) * 16 + lr;
            out[(size_t)n * HF + o] = acc[t][r] + bias[o];
        }
        // score tile 16: cols 0..7 = s_src per head, 8..15 = s_trg per head
        s_pair[n * 16 + lr] = acc[16][r];
    }
}

// ---------------------------------------------------------------------------
// CSR count (by target); block 0 also computes ctp[h] = <Wt[h,:], a_tp[h,:]>
// ---------------------------------------------------------------------------
__global__ __launch_bounds__(256) void k_count(const int* __restrict__ trg,
                                               int* __restrict__ deg,
                                               const float* __restrict__ Wt,
                                               const float* __restrict__ a_tp,
                                               float* __restrict__ ctp, int E)
{
    if (blockIdx.x == 0 && threadIdx.x < NH) {
        int h = threadIdx.x;
        float s = 0.f;
        #pragma unroll
        for (int f = 0; f < FO; ++f) s += Wt[h * FO + f] * a_tp[h * FO + f];
        ctp[h] = s;
    }
    int e4 = blockIdx.x * blockDim.x + threadIdx.x;
    if (e4 * 4 < E) {
        int4 t = reinterpret_cast<const int4*>(trg)[e4];
        atomicAdd(&deg[t.x], 1);
        atomicAdd(&deg[t.y], 1);
        atomicAdd(&deg[t.z], 1);
        atomicAdd(&deg[t.w], 1);
    }
}

// ---------------------------------------------------------------------------
// 3-phase exclusive scan of deg -> pos
// ---------------------------------------------------------------------------
__global__ __launch_bounds__(256) void k_scan1(const int* __restrict__ deg,
                                               int* __restrict__ partial)
{
    __shared__ int lds[256];
    int t = threadIdx.x, i = blockIdx.x * 256 + t;
    lds[t] = (i < Nn) ? deg[i] : 0;
    __syncthreads();
    for (int off = 128; off > 0; off >>= 1) {
        if (t < off) lds[t] += lds[t + off];
        __syncthreads();
    }
    if (t == 0) partial[blockIdx.x] = lds[0];
}

__global__ __launch_bounds__(256) void k_scan2(const int* __restrict__ partial,
                                               int* __restrict__ base)
{
    __shared__ int lds[256];
    int t = threadIdx.x;
    int v = (t < NSCAN) ? partial[t] : 0;
    lds[t] = v;
    __syncthreads();
    for (int off = 1; off < 256; off <<= 1) {
        int u = (t >= off) ? lds[t - off] : 0;
        __syncthreads();
        lds[t] += u;
        __syncthreads();
    }
    if (t < NSCAN) base[t] = lds[t] - v;   // exclusive prefix of partials
}

__global__ __launch_bounds__(256) void k_scan3(const int* __restrict__ deg,
                                               const int* __restrict__ base,
                                               int* __restrict__ pos)
{
    __shared__ int lds[256];
    int t = threadIdx.x, i = blockIdx.x * 256 + t;
    int v = (i < Nn) ? deg[i] : 0;
    lds[t] = v;
    __syncthreads();
    for (int off = 1; off < 256; off <<= 1) {
        int u = (t >= off) ? lds[t - off] : 0;
        __syncthreads();
        lds[t] += u;
        __syncthreads();
    }
    if (i < Nn) pos[i] = base[blockIdx.x] + lds[t] - v;   // exclusive prefix
}

// fill: pos[n] bumps exclusive -> inclusive; row n spans
// [ (n ? pos[n-1] : 0), pos[n] ).  epk2 = { src|trg<<16, f16(prob) }  (8B)
__global__ __launch_bounds__(256) void k_fill(
    const int* __restrict__ src, const int* __restrict__ trg,
    const float* __restrict__ prob, int* __restrict__ pos,
    uint2* __restrict__ epk2, int E)
{
    int e4 = blockIdx.x * blockDim.x + threadIdx.x;
    if (e4 * 4 >= E) return;
    int4   s4 = reinterpret_cast<const int4*>(src)[e4];
    int4   t4 = reinterpret_cast<const int4*>(trg)[e4];
    float4 p4 = reinterpret_cast<const float4*>(prob)[e4];
    int    sv[4] = {s4.x, s4.y, s4.z, s4.w};
    int    tv[4] = {t4.x, t4.y, t4.z, t4.w};
    float  pv[4] = {p4.x, p4.y, p4.z, p4.w};
    #pragma unroll
    for (int i = 0; i < 4; ++i) {
        int slot = atomicAdd(&pos[tv[i]], 1);
        uint2 pk;
        pk.x = (unsigned int)sv[i] | ((unsigned int)tv[i] << 16);
        pk.y = (unsigned int)__half_as_ushort(__float2half_rn(pv[i]));
        epk2[slot] = pk;
    }
}

// ---------------------------------------------------------------------------
// Edge-weight precompute: for each sorted slot e, exp(leaky(score)) for all
// 8 heads; pack (src | f16(ev) << 16) head-major: ewk[h][e].
// ---------------------------------------------------------------------------
__global__ __launch_bounds__(256) void k_ev(
    const uint2* __restrict__ epk2,
    const float* __restrict__ s_pair, const float* __restrict__ ctp,
    unsigned int* __restrict__ ewk, int E)
{
    int e = blockIdx.x * 256 + threadIdx.x;
    if (e >= E) return;
    const uint2 pk = epk2[e];
    const int s = pk.x & 0xFFFF;
    const int t = pk.x >> 16;
    const float p = __half2float(__ushort_as_half((unsigned short)pk.y));

    const float4* sp = reinterpret_cast<const float4*>(s_pair);
    float4 ss0 = sp[s * 4 + 0];
    float4 ss1 = sp[s * 4 + 1];
    float4 st0 = sp[t * 4 + 2];
    float4 st1 = sp[t * 4 + 3];
    float ssv[8] = {ss0.x, ss0.y, ss0.z, ss0.w, ss1.x, ss1.y, ss1.z, ss1.w};
    float stv[8] = {st0.x, st0.y, st0.z, st0.w, st1.x, st1.y, st1.z, st1.w};

    #pragma unroll
    for (int h = 0; h < NH; ++h) {
        float sc = ssv[h] + stv[h] + ctp[h] * p;
        sc = sc >= 0.f ? sc : 0.2f * sc;
        float ev = __expf(sc);
        ewk[(size_t)h * E + e] = (unsigned int)s |
            ((unsigned int)__half_as_ushort(__float2half_rn(ev)) << 16);
    }
}

// ---------------------------------------------------------------------------
// Gather, XCD-pinned heads (h = blockIdx.x & 7). One wave per (node, head);
// lanes = 8 edge-slots x 8 feature-pairs (half2 proj). Inner loop per edge:
// one 4B broadcast (ewk) + one 4B half2 gather + 3 FMA.
// ---------------------------------------------------------------------------
__global__ __launch_bounds__(256) void k_gather(
    const unsigned int* __restrict__ ewk, const int* __restrict__ pos,
    const __half2* __restrict__ projH, float* __restrict__ out, int E)
{
    const int bid = blockIdx.x;
    const int h   = bid & 7;                   // XCD-pinned head
    const int nb  = bid >> 3;                  // 0..12499
    const int wv  = threadIdx.x >> 6;
    const int lane = threadIdx.x & 63;
    const int n = nb * 4 + wv;                 // 50000 = 12500*4, always valid
    const int es = lane >> 3;                  // edge slot 0..7
    const int f2 = lane & 7;                   // feature pair 0..7

    const int jb = (n == 0) ? 0 : pos[n - 1];
    const int je = pos[n];
    const unsigned int* __restrict__ ew = ewk + (size_t)h * E;
    const __half2* __restrict__ psl = projH + (size_t)h * Nn * (FO / 2);

    float num0 = 0.f, num1 = 0.f, den = 0.f;
    int j = jb + es;
    // 2x unrolled: two independent gather chains in flight
    for (; j + 8 < je; j += 16) {
        const unsigned int u0 = ew[j];
        const unsigned int u1 = ew[j + 8];
        const int s0 = u0 & 0xFFFF;
        const int s1 = u1 & 0xFFFF;
        const __half2 g0 = psl[s0 * (FO / 2) + f2];
        const __half2 g1 = psl[s1 * (FO / 2) + f2];
        const float ev0 = __half2float(__ushort_as_half((unsigned short)(u0 >> 16)));
        const float ev1 = __half2float(__ushort_as_half((unsigned short)(u1 >> 16)));
        const float2 G0 = __half22float2(g0);
        const float2 G1 = __half22float2(g1);
        den  += ev0 + ev1;
        num0 += ev0 * G0.x + ev1 * G1.x;
        num1 += ev0 * G0.y + ev1 * G1.y;
    }
    if (j < je) {
        const unsigned int u = ew[j];
        const int s = u & 0xFFFF;
        const float ev = __half2float(__ushort_as_half((unsigned short)(u >> 16)));
        const float2 G = __half22float2(psl[s * (FO / 2) + f2]);
        den  += ev;
        num0 += ev * G.x;
        num1 += ev * G.y;
    }

    #pragma unroll
    for (int m = 8; m <= 32; m <<= 1) {
        num0 += __shfl_xor(num0, m, 64);
        num1 += __shfl_xor(num1, m, 64);
        den  += __shfl_xor(den,  m, 64);
    }

    if (es == 0) {
        const int idx = n * HF + h * FO + f2 * 2;
        const float inv = 1.f / (den + 1e-16f);
        float2 o = *reinterpret_cast<float2*>(&out[idx]);  // skip+bias
        float v0 = o.x + num0 * inv;
        float v1 = o.y + num1 * inv;
        v0 = v0 > 0.f ? v0 : expm1f(v0);
        v1 = v1 > 0.f ? v1 : expm1f(v1);
        *reinterpret_cast<float2*>(&out[idx]) = make_float2(v0, v1);
    }
}

// ---------------------------------------------------------------------------
extern "C" void kernel_launch(void* const* d_in, const int* in_sizes, int n_in,
                              void* d_out, int out_size, void* d_ws, size_t ws_size,
                              hipStream_t stream)
{
    const float* x     = (const float*)d_in[0];
    const int*   ei    = (const int*)d_in[1];
    const float* prob  = (const float*)d_in[2];
    const float* Wp    = (const float*)d_in[3];
    const float* Wt    = (const float*)d_in[4];
    const float* a_src = (const float*)d_in[5];
    const float* a_trg = (const float*)d_in[6];
    const float* a_tp  = (const float*)d_in[7];
    const float* Wskip = (const float*)d_in[8];
    const float* bias  = (const float*)d_in[9];
    float* out = (float*)d_out;

    const int E = in_sizes[2];        // edge_prob element count = E
    const int* src = ei;              // edge_index row 0
    const int* trg = ei + E;          // edge_index row 1

    // Workspace layout (~48.7 MB); all blocks 16B-aligned by construction
    char* wsb = (char*)d_ws;
    __half* projH  = (__half*)wsb;                      // Nn*HF f16 (12.8 MB)
    float* s_pair  = (float*)(wsb + (size_t)Nn*HF*2);   // Nn*16     (3.2 MB)
    float* ctp     = s_pair + (size_t)Nn * 16;          // 16 floats
    _Float16* Wh   = (_Float16*)(ctp + 16);             // 272*128   (68 KB)
    uint2* epk2    = (uint2*)(Wh + (size_t)NWR * FIN);  // E         (6.4 MB)
    unsigned int* ewk = (unsigned int*)(epk2 + E);      // NH*E      (25.6 MB)
    int*   deg     = (int*)(ewk + (size_t)NH * E);      // Nn
    int*   pos     = deg + Nn;                          // Nn
    int*   partial = pos + Nn;                          // NSCAN (pad 256)
    int*   base    = partial + 256;                     // NSCAN (pad 256)

    hipMemsetAsync(deg, 0, (size_t)Nn * sizeof(int), stream);
    k_count<<<(E / 4 + 255) / 256, 256, 0, stream>>>(trg, deg, Wt, a_tp, ctp, E);
    k_scan1<<<NSCAN, 256, 0, stream>>>(deg, partial);
    k_scan2<<<1, 256, 0, stream>>>(partial, base);
    k_scan3<<<NSCAN, 256, 0, stream>>>(deg, base, pos);
    k_fill<<<(E / 4 + 255) / 256, 256, 0, stream>>>(src, trg, prob, pos, epk2, E);
    k_prep<<<NWR, 128, 0, stream>>>(Wp, Wskip, a_src, a_trg, Wh);
    k_node<<<Nn / 16, 64, 0, stream>>>(x, Wh, bias, projH, out, s_pair);
    k_ev<<<(E + 255) / 256, 256, 0, stream>>>(epk2, s_pair, ctp, ewk, E);
    k_gather<<<NH * (Nn / 4), 256, 0, stream>>>(ewk, pos,
                                                (const __half2*)projH, out, E);
}

// Round 8
// 197.466 us; speedup vs baseline: 4.1102x; 1.4275x over previous
//
#include <hip/hip_runtime.h>
#include <hip/hip_fp16.h>
#include <math.h>

// Problem constants (from reference)
constexpr int Nn  = 50000;   // nodes
constexpr int FIN = 128;     // input features
constexpr int NH  = 8;       // heads
constexpr int FO  = 16;      // features per head
constexpr int HF  = 128;     // NH*FO
constexpr int NWR = 272;     // Wh rows: Wp(128) | Wskip(128) | Va_src(8) | Va_trg(8)
constexpr int NSCAN = (Nn + 255) / 256;         // 196 scan blocks

typedef _Float16 f16x8 __attribute__((ext_vector_type(8)));
typedef float    f32x4 __attribute__((ext_vector_type(4)));

// ---------------------------------------------------------------------------
// Weight prep: Wh[272][128] f16 =
//   rows   0..127 : Wp
//   rows 128..255 : Wskip
//   rows 256..263 : Va_src[h][k] = sum_f a_src[h,f] * Wp[h*16+f][k]
//   rows 264..271 : Va_trg[h][k] = sum_f a_trg[h,f] * Wp[h*16+f][k]
// ---------------------------------------------------------------------------
__global__ __launch_bounds__(128) void k_prep(
    const float* __restrict__ Wp, const float* __restrict__ Wskip,
    const float* __restrict__ a_src, const float* __restrict__ a_trg,
    _Float16* __restrict__ Wh)
{
    const int o = blockIdx.x;   // 0..271
    const int k = threadIdx.x;  // 0..127
    float v;
    if (o < 128)      v = Wp[o * FIN + k];
    else if (o < 256) v = Wskip[(o - 128) * FIN + k];
    else if (o < 264) {
        const int h = o - 256;
        float s = 0.f;
        #pragma unroll
        for (int f = 0; f < FO; ++f)
            s += a_src[h * FO + f] * Wp[(h * FO + f) * FIN + k];
        v = s;
    } else {
        const int h = o - 264;
        float s = 0.f;
        #pragma unroll
        for (int f = 0; f < FO; ++f)
            s += a_trg[h * FO + f] * Wp[(h * FO + f) * FIN + k];
        v = s;
    }
    Wh[o * FIN + k] = (_Float16)v;
}

// ---------------------------------------------------------------------------
// Node GEMM via MFMA f16: one wave per 16-node stripe, C = x @ Wh^T.
// 17 N-tiles x 4 K-steps = 68 mfma_f32_16x16x32_f16.
// Epilogue: projA[n][h][f] f16 (node-major, 256B per node),
//           out = skip + bias, s_pair[n][0..7]=s_src, [8..15]=s_trg.
// ---------------------------------------------------------------------------
__global__ __launch_bounds__(64) void k_node(
    const float* __restrict__ x, const _Float16* __restrict__ Wh,
    const float* __restrict__ bias,
    __half* __restrict__ projA, float* __restrict__ out,
    float* __restrict__ s_pair)
{
    const int n0 = blockIdx.x * 16;            // 3125 * 16 = 50000 exactly
    const int l  = threadIdx.x;                // 0..63
    const int lr = l & 15;
    const int kb = l >> 4;                     // k-block 0..3

    f16x8 a[4];
    const float* xr = x + (size_t)(n0 + lr) * FIN + kb * 8;
    #pragma unroll
    for (int ks = 0; ks < 4; ++ks) {
        float4 u0 = *reinterpret_cast<const float4*>(xr + ks * 32);
        float4 u1 = *reinterpret_cast<const float4*>(xr + ks * 32 + 4);
        a[ks][0] = (_Float16)u0.x; a[ks][1] = (_Float16)u0.y;
        a[ks][2] = (_Float16)u0.z; a[ks][3] = (_Float16)u0.w;
        a[ks][4] = (_Float16)u1.x; a[ks][5] = (_Float16)u1.y;
        a[ks][6] = (_Float16)u1.z; a[ks][7] = (_Float16)u1.w;
    }

    f32x4 acc[17];
    #pragma unroll
    for (int t = 0; t < 17; ++t) acc[t] = (f32x4){0.f, 0.f, 0.f, 0.f};

    const _Float16* wb = Wh + (size_t)lr * FIN + kb * 8;
    #pragma unroll
    for (int t = 0; t < 17; ++t) {
        const _Float16* wt = wb + (size_t)t * 16 * FIN;
        #pragma unroll
        for (int ks = 0; ks < 4; ++ks) {
            f16x8 b = *reinterpret_cast<const f16x8*>(wt + ks * 32);
            acc[t] = __builtin_amdgcn_mfma_f32_16x16x32_f16(a[ks], b, acc[t], 0, 0, 0);
        }
    }

    #pragma unroll
    for (int r = 0; r < 4; ++r) {
        const int n = n0 + kb * 4 + r;
        // proj heads (tiles 0..7), node-major f16: projA[n][t][lr]
        #pragma unroll
        for (int t = 0; t < 8; ++t)
            projA[(size_t)n * HF + t * FO + lr] = __float2half_rn(acc[t][r]);
        // skip + bias (tiles 8..15) -> output accumulator
        #pragma unroll
        for (int t = 8; t < 16; ++t) {
            const int o = (t - 8) * 16 + lr;
            out[(size_t)n * HF + o] = acc[t][r] + bias[o];
        }
        // score tile 16: cols 0..7 = s_src per head, 8..15 = s_trg per head
        s_pair[n * 16 + lr] = acc[16][r];
    }
}

// ---------------------------------------------------------------------------
// CSR count (by target); block 0 also computes ctp[h] = <Wt[h,:], a_tp[h,:]>
// ---------------------------------------------------------------------------
__global__ __launch_bounds__(256) void k_count(const int* __restrict__ trg,
                                               int* __restrict__ deg,
                                               const float* __restrict__ Wt,
                                               const float* __restrict__ a_tp,
                                               float* __restrict__ ctp, int E)
{
    if (blockIdx.x == 0 && threadIdx.x < NH) {
        int h = threadIdx.x;
        float s = 0.f;
        #pragma unroll
        for (int f = 0; f < FO; ++f) s += Wt[h * FO + f] * a_tp[h * FO + f];
        ctp[h] = s;
    }
    int e4 = blockIdx.x * blockDim.x + threadIdx.x;
    if (e4 * 4 < E) {
        int4 t = reinterpret_cast<const int4*>(trg)[e4];
        atomicAdd(&deg[t.x], 1);
        atomicAdd(&deg[t.y], 1);
        atomicAdd(&deg[t.z], 1);
        atomicAdd(&deg[t.w], 1);
    }
}

// ---------------------------------------------------------------------------
// Scan: per-block sums, then fused (block-scan of partials redundantly per
// block) + per-element exclusive scan -> pos.
// ---------------------------------------------------------------------------
__global__ __launch_bounds__(256) void k_scan1(const int* __restrict__ deg,
                                               int* __restrict__ partial)
{
    __shared__ int lds[256];
    int t = threadIdx.x, i = blockIdx.x * 256 + t;
    lds[t] = (i < Nn) ? deg[i] : 0;
    __syncthreads();
    for (int off = 128; off > 0; off >>= 1) {
        if (t < off) lds[t] += lds[t + off];
        __syncthreads();
    }
    if (t == 0) partial[blockIdx.x] = lds[0];
}

__global__ __launch_bounds__(256) void k_scan3(const int* __restrict__ deg,
                                               const int* __restrict__ partial,
                                               int* __restrict__ pos)
{
    __shared__ int lds[256], lds2[256];
    const int t = threadIdx.x;
    const int i = blockIdx.x * 256 + t;
    // redundant inclusive scan of partials in every block
    lds2[t] = (t < NSCAN) ? partial[t] : 0;
    __syncthreads();
    for (int off = 1; off < 256; off <<= 1) {
        int u = (t >= off) ? lds2[t - off] : 0;
        __syncthreads();
        lds2[t] += u;
        __syncthreads();
    }
    const int base = (blockIdx.x == 0) ? 0 : lds2[blockIdx.x - 1];
    // per-element exclusive scan
    int v = (i < Nn) ? deg[i] : 0;
    lds[t] = v;
    __syncthreads();
    for (int off = 1; off < 256; off <<= 1) {
        int u = (t >= off) ? lds[t - off] : 0;
        __syncthreads();
        lds[t] += u;
        __syncthreads();
    }
    if (i < Nn) pos[i] = base + lds[t] - v;
}

// fill: pos[n] bumps exclusive -> inclusive; row n spans
// [ (n ? pos[n-1] : 0), pos[n] ).  spk = src(16b) | f16(prob)(16b), 4B/edge.
__global__ __launch_bounds__(256) void k_fill(
    const int* __restrict__ src, const int* __restrict__ trg,
    const float* __restrict__ prob, int* __restrict__ pos,
    unsigned int* __restrict__ spk, int E)
{
    int e4 = blockIdx.x * blockDim.x + threadIdx.x;
    if (e4 * 4 >= E) return;
    int4   s4 = reinterpret_cast<const int4*>(src)[e4];
    int4   t4 = reinterpret_cast<const int4*>(trg)[e4];
    float4 p4 = reinterpret_cast<const float4*>(prob)[e4];
    int    sv[4] = {s4.x, s4.y, s4.z, s4.w};
    int    tv[4] = {t4.x, t4.y, t4.z, t4.w};
    float  pv[4] = {p4.x, p4.y, p4.z, p4.w};
    #pragma unroll
    for (int i = 0; i < 4; ++i) {
        int slot = atomicAdd(&pos[tv[i]], 1);
        spk[slot] = (unsigned int)sv[i] |
            ((unsigned int)__half_as_ushort(__float2half_rn(pv[i])) << 16);
    }
}

// ---------------------------------------------------------------------------
// Fused gather: one wave per node; lanes = 8 heads x 8 feature-pairs.
// All lanes share the node's edge range (zero divergence, zero shuffles).
// Per edge: spk dword (broadcast) + s_pair[s] gather + projA[s] 256B
// contiguous wave-read; score+exp computed inline (each head's 8 lanes
// duplicate it — free in wave-instrs). Epilogue: all 128 outputs as
// coalesced float2 stores.
// ---------------------------------------------------------------------------
__global__ __launch_bounds__(256) void k_gather(
    const unsigned int* __restrict__ spk, const int* __restrict__ pos,
    const float* __restrict__ s_pair, const float* __restrict__ ctp,
    const __half2* __restrict__ projA, float* __restrict__ out)
{
    const int wv   = threadIdx.x >> 6;
    const int n    = blockIdx.x * 4 + wv;      // 12500*4 = 50000 exactly
    const int lane = threadIdx.x & 63;
    const int h    = lane >> 3;                // head 0..7
    const int f2   = lane & 7;                 // feature pair 0..7

    const int jb = (n == 0) ? 0 : pos[n - 1];
    const int je = pos[n];
    const float st  = s_pair[n * 16 + 8 + h];
    const float cth = ctp[h];
    const float* __restrict__ ssl = s_pair + h;          // [s*16]
    const __half2* __restrict__ pA = projA + h * 8 + f2; // [s*64]

    float num0 = 0.f, num1 = 0.f, den = 0.f;
    int j = jb;
    for (; j + 1 < je; j += 2) {               // 2 independent chains
        const unsigned int pk0 = spk[j];
        const unsigned int pk1 = spk[j + 1];
        const int s0 = pk0 & 0xFFFF;
        const int s1 = pk1 & 0xFFFF;
        const float p0 = __half2float(__ushort_as_half((unsigned short)(pk0 >> 16)));
        const float p1 = __half2float(__ushort_as_half((unsigned short)(pk1 >> 16)));
        const float ss0 = ssl[s0 * 16];
        const float ss1 = ssl[s1 * 16];
        const __half2 g0 = pA[s0 * 64];
        const __half2 g1 = pA[s1 * 64];
        float sc0 = ss0 + st + cth * p0;
        float sc1 = ss1 + st + cth * p1;
        sc0 = fmaxf(sc0, 0.2f * sc0);          // leaky_relu(0.2)
        sc1 = fmaxf(sc1, 0.2f * sc1);
        const float ev0 = __expf(sc0);
        const float ev1 = __expf(sc1);
        const float2 G0 = __half22float2(g0);
        const float2 G1 = __half22float2(g1);
        den  += ev0 + ev1;
        num0 += ev0 * G0.x + ev1 * G1.x;
        num1 += ev0 * G0.y + ev1 * G1.y;
    }
    if (j < je) {
        const unsigned int pk = spk[j];
        const int s = pk & 0xFFFF;
        const float p = __half2float(__ushort_as_half((unsigned short)(pk >> 16)));
        float sc = ssl[s * 16] + st + cth * p;
        sc = fmaxf(sc, 0.2f * sc);
        const float ev = __expf(sc);
        const float2 G = __half22float2(pA[s * 64]);
        den  += ev;
        num0 += ev * G.x;
        num1 += ev * G.y;
    }

    const float inv = 1.f / (den + 1e-16f);
    const int idx = n * HF + h * FO + f2 * 2;
    float2 o = *reinterpret_cast<const float2*>(&out[idx]);  // skip+bias
    float v0 = o.x + num0 * inv;
    float v1 = o.y + num1 * inv;
    v0 = v0 > 0.f ? v0 : expm1f(v0);
    v1 = v1 > 0.f ? v1 : expm1f(v1);
    *reinterpret_cast<float2*>(&out[idx]) = make_float2(v0, v1);
}

// ---------------------------------------------------------------------------
extern "C" void kernel_launch(void* const* d_in, const int* in_sizes, int n_in,
                              void* d_out, int out_size, void* d_ws, size_t ws_size,
                              hipStream_t stream)
{
    const float* x     = (const float*)d_in[0];
    const int*   ei    = (const int*)d_in[1];
    const float* prob  = (const float*)d_in[2];
    const float* Wp    = (const float*)d_in[3];
    const float* Wt    = (const float*)d_in[4];
    const float* a_src = (const float*)d_in[5];
    const float* a_trg = (const float*)d_in[6];
    const float* a_tp  = (const float*)d_in[7];
    const float* Wskip = (const float*)d_in[8];
    const float* bias  = (const float*)d_in[9];
    float* out = (float*)d_out;

    const int E = in_sizes[2];        // edge_prob element count = E
    const int* src = ei;              // edge_index row 0
    const int* trg = ei + E;          // edge_index row 1

    // Workspace layout (~20 MB); all blocks 16B-aligned by construction
    char* wsb = (char*)d_ws;
    __half* projA  = (__half*)wsb;                      // Nn*HF f16 (12.8 MB)
    float* s_pair  = (float*)(wsb + (size_t)Nn*HF*2);   // Nn*16     (3.2 MB)
    float* ctp     = s_pair + (size_t)Nn * 16;          // 16 floats
    _Float16* Wh   = (_Float16*)(ctp + 16);             // 272*128   (68 KB)
    unsigned int* spk = (unsigned int*)(Wh + (size_t)NWR * FIN); // E (3.2 MB)
    int*   deg     = (int*)(spk + E);                   // Nn
    int*   pos     = deg + Nn;                          // Nn
    int*   partial = pos + Nn;                          // NSCAN (pad 256)

    hipMemsetAsync(deg, 0, (size_t)Nn * sizeof(int), stream);
    k_count<<<(E / 4 + 255) / 256, 256, 0, stream>>>(trg, deg, Wt, a_tp, ctp, E);
    k_scan1<<<NSCAN, 256, 0, stream>>>(deg, partial);
    k_scan3<<<NSCAN, 256, 0, stream>>>(deg, partial, pos);
    k_fill<<<(E / 4 + 255) / 256, 256, 0, stream>>>(src, trg, prob, pos, spk, E);
    k_prep<<<NWR, 128, 0, stream>>>(Wp, Wskip, a_src, a_trg, Wh);
    k_node<<<Nn / 16, 64, 0, stream>>>(x, Wh, bias, projA, out, s_pair);
    k_gather<<<Nn / 4, 256, 0, stream>>>(spk, pos, s_pair, ctp,
                                         (const __half2*)projA, out);
}